// Round 11
// baseline (1089.563 us; speedup 1.0000x reference)
//
#include <hip/hip_runtime.h>
#include <cstdint>
#include <cstddef>

typedef _Float16 half_t;
typedef _Float16 half8 __attribute__((ext_vector_type(8)));
typedef float f32x4 __attribute__((ext_vector_type(4)));

constexpr int NN = 131072;    // nodes
constexpr int NE = 1048576;   // edges
constexpr int NPER = 512;

#define DEVINL __device__ __forceinline__

DEVINL float sigm_(float x){ float e = __expf(-x); return __builtin_amdgcn_rcpf(1.f+e); }
DEVINL float tanh_(float x){
  x = fminf(15.f, fmaxf(-15.f, x));
  float e = __expf(-2.f*x);
  return (1.f-e)*__builtin_amdgcn_rcpf(1.f+e);
}

// LDS-only barrier: no vmcnt drain (keeps global loads/stores in flight)
#define LDS_BARRIER() asm volatile("s_waitcnt lgkmcnt(0)\ns_barrier" ::: "memory")

// ---------------- tiny precompute kernels ----------------

__global__ void const_kernel(const float* __restrict__ gatWe,
                             const float* __restrict__ attE, const float* __restrict__ eW,
                             const float* __restrict__ eb, float* __restrict__ cc){
  int l = blockIdx.x, k = threadIdx.x;   // 3 blocks x 64 threads
  const float* Wel = gatWe + l*4096;
  float s3=0.f;
  for (int j=0;j<64;j++) s3 += Wel[k*64+j]*attE[l*64+j];
  float c0 = eW[k]*s3, c1 = eW[64+k]*s3, cb = eb[k]*s3;
  for (int off=1; off<64; off<<=1){
    c0 += __shfl_xor(c0,off); c1 += __shfl_xor(c1,off); cb += __shfl_xor(cb,off);
  }
  if (k==0){ cc[l]=c0; cc[3+l]=c1; cc[6+l]=cb; }
}

// pack/transpose weights to f16
__global__ void prep_pack(const float* __restrict__ wih_f, const float* __restrict__ wih_b,
                          const float* __restrict__ head_W1, const float* __restrict__ gat_W,
                          const float* __restrict__ bih_f, const float* __restrict__ bih_b,
                          const float* __restrict__ whh_f, const float* __restrict__ whh_b,
                          half_t* __restrict__ BcombT, half_t* __restrict__ W1T,
                          half_t* __restrict__ BTgat, float* __restrict__ bias_comb,
                          half_t* __restrict__ whh16){
  int gid = blockIdx.x*256 + threadIdx.x;
  if (gid < 147456){                       // BcombT: j<384 from wih_f else wih_b, k-contig
    int j = gid/192, k = gid%192;
    float v = (j<384)? wih_f[j*192+k] : wih_b[(j-384)*192+k];
    BcombT[gid] = (half_t)v;
  } else if (gid < 163840){                // W1T[n][k] = head_W1[k][n]
    int i = gid - 147456;
    int n = i>>8, k = i&255;
    W1T[i] = (half_t)head_W1[k*64+n];
  } else if (gid < 176128){                // BTgat[l][n][k] = gat_W[l][k][n]
    int i = gid - 163840;
    int l = i>>12, r = i&4095;
    int n = r>>6, k = r&63;
    BTgat[i] = (half_t)gat_W[l*4096 + k*64 + n];
  } else if (gid < 176896){
    int i = gid - 176128;                  // 0..767 (bih; bhh r,z folded by bias_fold)
    int j = (i<384)? i : i-384;
    bias_comb[i] = (i<384)? bih_f[j] : bih_b[j];
  } else if (gid < 275200){                // whh16: flat copy f then b (49152 each)
    int i = gid - 176896;
    float v = (i<49152)? whh_f[i] : whh_b[i-49152];
    whh16[i] = (half_t)v;
  }
}

__global__ void bias_fold(const float* __restrict__ bhh_f, const float* __restrict__ bhh_b,
                          float* __restrict__ bias_comb){
  int i = threadIdx.x + blockIdx.x*256;    // 0..511
  if (i < 256)      bias_comb[i]       += bhh_f[i];
  else if (i < 512) bias_comb[i+128]   += bhh_b[i-256];  // 384..639
}

// ---------------- node embedding ----------------
__global__ __launch_bounds__(256) void embed_kernel(const float* __restrict__ x,
                            const float* __restrict__ nW, const float* __restrict__ nb,
                            half_t* __restrict__ h){
  int gid = blockIdx.x*256 + threadIdx.x;
  int n = gid>>6, j = gid&63;
  float v = x[2*n]*nW[j] + x[2*n+1]*nW[64+j] + nb[j];
  h[(size_t)n*64+j] = (half_t)v;
}

// ---------------- edge preprocessing ----------------
__global__ __launch_bounds__(256) void deg_count(const int* __restrict__ ei,
                          int* __restrict__ deg, int* __restrict__ tmp){
  int e = blockIdx.x*256 + threadIdx.x;
  int dt = ei[NE+e];
  tmp[e] = atomicAdd(&deg[dt],1);
}

__global__ __launch_bounds__(256) void scan1(const int* __restrict__ deg, int* __restrict__ rowstart,
                      int* __restrict__ bsum){
  __shared__ int sc[256];
  int b=blockIdx.x, t=threadIdx.x, i=b*256+t;
  int v=deg[i]; sc[t]=v; __syncthreads();
  for (int off=1; off<256; off<<=1){
    int tv = (t>=off)? sc[t-off] : 0;
    __syncthreads(); sc[t]+=tv; __syncthreads();
  }
  rowstart[i]=sc[t]-v;
  if (t==255) bsum[b]=sc[255];
}
__global__ void scan2(int* __restrict__ bsum){   // 1 block x 512
  __shared__ int sc[512];
  int t=threadIdx.x; int v=bsum[t]; sc[t]=v; __syncthreads();
  for (int off=1; off<512; off<<=1){
    int tv = (t>=off)? sc[t-off] : 0;
    __syncthreads(); sc[t]+=tv; __syncthreads();
  }
  bsum[t]=sc[t]-v;
}
__global__ __launch_bounds__(256) void scan3(int* __restrict__ rowstart, const int* __restrict__ bsum){
  int b=blockIdx.x, t=threadIdx.x, i=b*256+t;
  rowstart[i]+=bsum[b];
}

// one 16B record per edge slot: {src, ea0, ea1, dst}
__global__ __launch_bounds__(256) void fill2(const int* __restrict__ ei, const float* __restrict__ ea,
                      const int* __restrict__ rowstart, const int* __restrict__ tmp,
                      int4* __restrict__ rec){
  int e = blockIdx.x*256 + threadIdx.x;
  int dt = ei[NE+e];
  int slot = rowstart[dt] + tmp[e];
  int4 r;
  r.x = ei[e];
  r.y = __float_as_int(ea[2*e]);
  r.z = __float_as_int(ea[2*e+1]);
  r.w = dt;
  rec[slot] = r;
}

__global__ __launch_bounds__(256) void means_kernel(const int* __restrict__ deg, const int* __restrict__ rowstart,
                         const int4* __restrict__ rec, float2* __restrict__ m01){
  int n = blockIdx.x*256 + threadIdx.x;
  int st = rowstart[n], cnt = deg[n];
  float s0=0.f, s1=0.f;
  for (int i=0;i<cnt;i++){
    int4 r = rec[st+i];
    s0 += __int_as_float(r.y);
    s1 += __int_as_float(r.z);
  }
  float inv = 1.f/(float)max(cnt,1);
  float2 m; m.x = s0*inv; m.y = s1*inv;
  m01[n] = m;
}

// ---------------- xp GEMM with fused attention-logit epilogue ----------------
__global__ __launch_bounds__(256) void gemm_xp(const half_t* __restrict__ A, int lda,
                        const half_t* __restrict__ BT,
                        const float* __restrict__ attS, const float* __restrict__ attD,
                        half_t* __restrict__ xp, float* __restrict__ a_s, float* __restrict__ a_d){
  __shared__ half_t As[128*32];
  __shared__ half_t Bs[64*32];
  const int tid = threadIdx.x, m0 = blockIdx.x*128;
  const int w = tid>>6, lane = tid&63;
  const int lm = lane&15, quad = lane>>4;
  const int wm0 = w*32;
  f32x4 acc[2][4] = {};
  for (int k0=0;k0<64;k0+=32){
    {
      const int c0 = tid*2;
      #pragma unroll
      for (int u=0;u<2;u++){
        int c=c0+u; int row=c>>2; int off=(c&3)*8;
        *(half8*)(&As[row*32+off]) = *(const half8*)(&A[(size_t)(m0+row)*lda + k0 + off]);
      }
      int c=tid; int row=c>>2; int off=(c&3)*8;
      *(half8*)(&Bs[row*32+off]) = *(const half8*)(&BT[(size_t)row*64 + k0 + off]);
    }
    __syncthreads();
    half8 af[2], bf[4];
    #pragma unroll
    for (int nt=0;nt<4;nt++) bf[nt] = *(const half8*)(&Bs[(nt*16+lm)*32 + quad*8]);
    #pragma unroll
    for (int mt=0;mt<2;mt++) af[mt] = *(const half8*)(&As[(wm0+mt*16+lm)*32 + quad*8]);
    #pragma unroll
    for (int mt=0;mt<2;mt++)
      #pragma unroll
      for (int nt=0;nt<4;nt++)
        acc[mt][nt] = __builtin_amdgcn_mfma_f32_16x16x32_f16(af[mt], bf[nt], acc[mt][nt], 0,0,0);
    __syncthreads();
  }
  float vsv[4], vdv[4];
  #pragma unroll
  for (int nt=0;nt<4;nt++){ vsv[nt]=attS[nt*16+lm]; vdv[nt]=attD[nt*16+lm]; }
  #pragma unroll
  for (int mt=0;mt<2;mt++)
   #pragma unroll
   for (int r=0;r<4;r++){
    int m = m0+wm0+mt*16+quad*4+r;
    float ps=0.f, pd=0.f;
    #pragma unroll
    for (int nt=0;nt<4;nt++){
      float v = acc[mt][nt][r];
      xp[(size_t)m*64 + nt*16+lm] = (half_t)v;
      ps += v*vsv[nt]; pd += v*vdv[nt];
    }
    ps += __shfl_xor(ps,1); ps += __shfl_xor(ps,2); ps += __shfl_xor(ps,4); ps += __shfl_xor(ps,8);
    pd += __shfl_xor(pd,1); pd += __shfl_xor(pd,2); pd += __shfl_xor(pd,4); pd += __shfl_xor(pd,8);
    if (lm==0){ a_s[m]=ps; a_d[m]=pd; }
  }
}

// ---------------- slot-parallel edge softmax weight ----------------
__global__ __launch_bounds__(256) void edge_w(const int4* __restrict__ rec,
                       const float* __restrict__ a_s, const float* __restrict__ a_d,
                       const float* __restrict__ cc, int l, int2* __restrict__ sw){
  int s = blockIdx.x*256 + threadIdx.x;
  int4 r = rec[s];
  float al = a_s[r.x] + a_d[r.w]
           + __int_as_float(r.y)*cc[l] + __int_as_float(r.z)*cc[3+l] + cc[6+l];
  al = al>0.f? al : 0.2f*al;
  int2 o; o.x = r.x; o.y = __float_as_int(__expf(al));
  sw[s] = o;
}

// ---------------- graph-local LDS aggregate ----------------
// 1 block = 1 graph (512 threads, 8 waves). Stage xp[g] window (512x64 f16 = 64KB)
// into LDS; each wave walks 64 nodes, gathering rows from LDS (2-way bank = free).
__global__ __launch_bounds__(512,1) void agg_lds(const int* __restrict__ rowstart, const int* __restrict__ deg,
                          const int2* __restrict__ sw,
                          const float* __restrict__ a_s, const float* __restrict__ a_d,
                          const float2* __restrict__ m01, const float* __restrict__ cc, int l,
                          const half_t* __restrict__ xp, const float* __restrict__ bias,
                          half_t* __restrict__ hjk){
  __shared__ half_t xs[512*64];   // 64 KB
  const int g = blockIdx.x;
  const int tid = threadIdx.x;
  {
    const half8* srcp = (const half8*)(xp + (size_t)g*32768);
    half8* dstp = (half8*)xs;
    #pragma unroll
    for (int i=0;i<8;i++)
      dstp[tid + i*512] = srcp[tid + i*512];
  }
  __syncthreads();
  const int w = tid>>6, lane = tid&63;
  const float bv = bias[lane];
  const float c0=cc[l], c1=cc[3+l], cb=cc[6+l];
  const int nbase = g*512 + w*64;
  for (int i=0;i<64;i++){
    int n = nbase + i;
    int st = rowstart[n], cnt = deg[n];
    float acc=0.f, den=0.f;
    if (cnt>0){
      int2 p = sw[st];
      for (int k=0;k<cnt;k++){
        int2 pn;
        if (k+1<cnt) pn = sw[st+k+1];
        float ww = __int_as_float(p.y);
        den += ww;
        acc += ww*(float)xs[(p.x&511)*64 + lane];
        p = pn;
      }
    }
    float2 m = m01[n];
    float ael = cnt? (m.x*c0 + m.y*c1 + cb) : 0.f;
    float asl = a_s[n] + a_d[n] + ael;
    asl = asl>0.f? asl : 0.2f*asl;
    float wsf = __expf(asl);
    den += wsf;
    acc += wsf*(float)xs[(n&511)*64 + lane];
    float v = acc/den + bv;
    v = v>0.f? v : 0.01f*v;
    hjk[(size_t)n*192 + l*64 + lane] = (half_t)v;
  }
}

// ---------------- head GEMM with fused MLP-2 epilogue ----------------
__global__ __launch_bounds__(256) void gemm_head(const half_t* __restrict__ A,
                        const half_t* __restrict__ W1T, const float* __restrict__ b1,
                        const float* __restrict__ W2, const float* __restrict__ b2,
                        float* __restrict__ out){
  __shared__ half_t As[128*32];
  __shared__ half_t Bs[64*32];
  const int tid = threadIdx.x, m0 = blockIdx.x*128;
  const int w = tid>>6, lane = tid&63;
  const int lm = lane&15, quad = lane>>4;
  const int wm0 = w*32;
  f32x4 acc[2][4] = {};
  for (int k0=0;k0<256;k0+=32){
    {
      const int c0 = tid*2;
      #pragma unroll
      for (int u=0;u<2;u++){
        int c=c0+u; int row=c>>2; int off=(c&3)*8;
        *(half8*)(&As[row*32+off]) = *(const half8*)(&A[(size_t)(m0+row)*256 + k0 + off]);
      }
      int c=tid; int row=c>>2; int off=(c&3)*8;
      *(half8*)(&Bs[row*32+off]) = *(const half8*)(&W1T[(size_t)row*256 + k0 + off]);
    }
    __syncthreads();
    half8 af[2], bf[4];
    #pragma unroll
    for (int nt=0;nt<4;nt++) bf[nt] = *(const half8*)(&Bs[(nt*16+lm)*32 + quad*8]);
    #pragma unroll
    for (int mt=0;mt<2;mt++) af[mt] = *(const half8*)(&As[(wm0+mt*16+lm)*32 + quad*8]);
    #pragma unroll
    for (int mt=0;mt<2;mt++)
      #pragma unroll
      for (int nt=0;nt<4;nt++)
        acc[mt][nt] = __builtin_amdgcn_mfma_f32_16x16x32_f16(af[mt], bf[nt], acc[mt][nt], 0,0,0);
    __syncthreads();
  }
  float b1v[4], w20[4], w21[4];
  #pragma unroll
  for (int nt=0;nt<4;nt++){
    int n = nt*16+lm;
    b1v[nt]=b1[n]; w20[nt]=W2[n*2]; w21[nt]=W2[n*2+1];
  }
  float b20=b2[0], b21=b2[1];
  #pragma unroll
  for (int mt=0;mt<2;mt++)
   #pragma unroll
   for (int r=0;r<4;r++){
    int m = m0+wm0+mt*16+quad*4+r;
    float p0=0.f, p1=0.f;
    #pragma unroll
    for (int nt=0;nt<4;nt++){
      float v = acc[mt][nt][r] + b1v[nt];
      v = v>0.f? v : 0.f;
      p0 += v*w20[nt]; p1 += v*w21[nt];
    }
    p0 += __shfl_xor(p0,1); p0 += __shfl_xor(p0,2); p0 += __shfl_xor(p0,4); p0 += __shfl_xor(p0,8);
    p1 += __shfl_xor(p1,1); p1 += __shfl_xor(p1,2); p1 += __shfl_xor(p1,4); p1 += __shfl_xor(p1,8);
    if (lm==0){
      out[(size_t)m*2]   = p0 + b20;
      out[(size_t)m*2+1] = p1 + b21;
    }
  }
}

// ---------------- fused GRU recurrence + next-chunk gx GEMM ----------------
__global__ __launch_bounds__(512,1) void gru_fused(
    const half_t* __restrict__ whh16, const float* __restrict__ bhh_f, const float* __restrict__ bhh_b,
    const half_t* __restrict__ gxf, const half_t* __restrict__ gxb,
    float* __restrict__ hstate, half_t* __restrict__ y, int c, int gruBlocks,
    const half_t* __restrict__ hjk, const half_t* __restrict__ BcombT, const float* __restrict__ biasc,
    half_t* __restrict__ gxf_n, half_t* __restrict__ gxb_n, int s0f, int s0b){
  __shared__ half_t h16[2][16][132];
  __shared__ half_t As[128*32];
  __shared__ half_t Bs[128*32];
  const int bid = blockIdx.x;
  const int tid = threadIdx.x;
  if (bid < gruBlocks){
    // ---------------- GRU path ----------------
    const int d = bid >> 4, gblk = bid & 15;
    const half_t* __restrict__ gx = d ? gxb : gxf;
    const float* bhh = d ? bhh_b : bhh_f;
    const int w = tid >> 6, lane = tid & 63;
    const int l15 = lane & 15, quad = lane >> 4;
    const int unit = w*16 + l15;

    half8 bf[3][4];
    float bhn = bhh[256 + unit];
    {
      const half_t* wbase = whh16 + (size_t)d*49152;
      #pragma unroll
      for (int g=0; g<3; g++){
        const half_t* wp = wbase + (size_t)(g*128 + unit)*128;
        #pragma unroll
        for (int kk=0; kk<4; kk++)
          bf[g][kk] = *(const half8*)(wp + kk*32 + quad*8);
      }
    }

    float hreg[4];
    #pragma unroll
    for (int r=0;r<4;r++)
      hreg[r] = hstate[((size_t)d*256 + gblk*16 + quad*4 + r)*128 + unit];
    #pragma unroll
    for (int r=0;r<4;r++)
      h16[0][quad*4+r][unit] = (half_t)hreg[r];

    const int jstep = d ? -384 : 384;
    const int ystep = d ? -256 : 256;
    const int j0 = d ? 127 : 0;
    const int pos0 = d ? (511 - c*128) : (c*128);
    const int gr = gblk*16 + quad*4;
    int gvo[4], yvo[4];
    #pragma unroll
    for (int r=0;r<4;r++){
      gvo[r] = ((gr+r)*128 + j0)*384 + unit;
      yvo[r] = ((gr+r)*512 + pos0)*256 + d*128 + unit;
    }

    half_t gva[12], gvb[12];
    #pragma unroll
    for (int g=0;g<3;g++)
      #pragma unroll
      for (int r=0;r<4;r++) gva[g*4+r] = gx[gvo[r] + g*128];
    #pragma unroll
    for (int r=0;r<4;r++) gvo[r] += jstep;
    LDS_BARRIER();

    auto step = [&](int rd, int wr, half_t* gc, half_t* gn, bool pf){
      if (pf){
        #pragma unroll
        for (int g=0;g<3;g++)
          #pragma unroll
          for (int r=0;r<4;r++) gn[g*4+r] = gx[gvo[r] + g*128];
        #pragma unroll
        for (int r=0;r<4;r++) gvo[r] += jstep;
      }
      half8 af[4];
      #pragma unroll
      for (int kk=0;kk<4;kk++)
        af[kk] = *(const half8*)(&h16[rd][l15][kk*32 + quad*8]);
      f32x4 P[3] = {};
      #pragma unroll
      for (int kk=0;kk<4;kk++)
        #pragma unroll
        for (int g=0;g<3;g++)
          P[g] = __builtin_amdgcn_mfma_f32_16x16x32_f16(af[kk], bf[g][kk], P[g], 0,0,0);
      #pragma unroll
      for (int r=0;r<4;r++){
        float rr = sigm_((float)gc[0*4+r] + P[0][r]);
        float zz = sigm_((float)gc[1*4+r] + P[1][r]);
        float nn = tanh_((float)gc[2*4+r] + rr*(P[2][r] + bhn));
        float hn = nn + zz*(hreg[r]-nn);
        hreg[r] = hn;
        h16[wr][quad*4+r][unit] = (half_t)hn;
        y[yvo[r]] = (half_t)hn;
        yvo[r] += ystep;
      }
      LDS_BARRIER();
    };
    for (int it=0; it<63; it++){
      step(0,1,gva,gvb,true);
      step(1,0,gvb,gva,true);
    }
    step(0,1,gva,gvb,true);
    step(1,0,gvb,gva,false);
    #pragma unroll
    for (int r=0;r<4;r++)
      hstate[((size_t)d*256 + gblk*16 + quad*4 + r)*128 + unit] = hreg[r];
  } else {
    // ---------------- gemm path (512 threads, 8 waves) ----------------
    const int gb = bid - gruBlocks;
    const int bx = gb & 255, by = gb >> 8;       // 256 x 6
    const int m0 = bx*128;
    const bool back = by >= 3;
    const int n0 = (back ? by-3 : by)*128;
    const int step0 = back ? s0b : s0f;
    half_t* C = back ? gxb_n : gxf_n;
    const half_t* BTh = BcombT + (back ? (size_t)384*192 : 0);
    const float* bh = biasc + (back ? 384 : 0);
    const int w = tid>>6, lane = tid&63;
    const int lm = lane&15, quad = lane>>4;
    const int wm0 = (w>>2)*64, wn0 = (w&3)*32;
    f32x4 acc[4][2] = {};
    for (int k0=0; k0<192; k0+=32){
      {
        int cidx = tid; int row = cidx>>2; int off = (cidx&3)*8;
        int m = m0+row;
        size_t arow = (size_t)(m>>7)*512 + step0 + (m&127);
        *(half8*)(&As[row*32+off]) = *(const half8*)(&hjk[arow*192 + k0 + off]);
        *(half8*)(&Bs[row*32+off]) = *(const half8*)(&BTh[(size_t)(n0+row)*192 + k0 + off]);
      }
      __syncthreads();
      half8 af[4], bfr[2];
      #pragma unroll
      for (int nt=0;nt<2;nt++) bfr[nt] = *(const half8*)(&Bs[(wn0+nt*16+lm)*32 + quad*8]);
      #pragma unroll
      for (int mt=0;mt<4;mt++) af[mt] = *(const half8*)(&As[(wm0+mt*16+lm)*32 + quad*8]);
      #pragma unroll
      for (int mt=0;mt<4;mt++)
        #pragma unroll
        for (int nt=0;nt<2;nt++)
          acc[mt][nt] = __builtin_amdgcn_mfma_f32_16x16x32_f16(af[mt], bfr[nt], acc[mt][nt], 0,0,0);
      __syncthreads();
    }
    #pragma unroll
    for (int mt=0;mt<4;mt++)
     #pragma unroll
     for (int nt=0;nt<2;nt++)
      #pragma unroll
      for (int r=0;r<4;r++){
        int m = m0+wm0+mt*16+quad*4+r;
        int n = n0+wn0+nt*16+lm;
        float v = acc[mt][nt][r] + bh[n];
        C[(size_t)m*384 + n] = (half_t)v;
      }
  }
}

// ---------------- launch ----------------
extern "C" void kernel_launch(void* const* d_in, const int* in_sizes, int n_in,
                              void* d_out, int out_size, void* d_ws, size_t ws_size,
                              hipStream_t stream) {
  const float* x       = (const float*)d_in[0];
  const float* ea      = (const float*)d_in[1];
  const float* node_W  = (const float*)d_in[2];
  const float* node_b  = (const float*)d_in[3];
  const float* eW      = (const float*)d_in[4];
  const float* eb      = (const float*)d_in[5];
  const float* gat_W   = (const float*)d_in[6];
  const float* gat_We  = (const float*)d_in[7];
  const float* attS    = (const float*)d_in[8];
  const float* attD    = (const float*)d_in[9];
  const float* attE    = (const float*)d_in[10];
  const float* gat_b   = (const float*)d_in[11];
  const float* wih_f   = (const float*)d_in[12];
  const float* whh_f   = (const float*)d_in[13];
  const float* bih_f   = (const float*)d_in[14];
  const float* bhh_f   = (const float*)d_in[15];
  const float* wih_b   = (const float*)d_in[16];
  const float* whh_b   = (const float*)d_in[17];
  const float* bih_b   = (const float*)d_in[18];
  const float* bhh_b   = (const float*)d_in[19];
  const float* head_W1 = (const float*)d_in[20];
  const float* head_b1 = (const float*)d_in[21];
  const float* head_W2 = (const float*)d_in[22];
  const float* head_b2 = (const float*)d_in[23];
  const int*   ei      = (const int*)d_in[24];
  float* out = (float*)d_out;
  char* ws = (char*)d_ws;
  (void)in_sizes; (void)n_in; (void)out_size; (void)ws_size;

  size_t o = 0;
  auto alloc = [&](size_t bytes)->size_t{ size_t r=o; o += (bytes+255)&~(size_t)255; return r; };
  // persistent region
  size_t o_cc     = alloc(16*4);
  size_t o_biasc  = alloc(768*4);
  size_t o_BcombT = alloc((size_t)768*192*2);
  size_t o_BTgat  = alloc((size_t)3*4096*2);
  size_t o_W1T    = alloc((size_t)64*256*2);
  size_t o_whh16  = alloc((size_t)2*49152*2);
  size_t o_hstate = alloc((size_t)2*256*128*4);
  size_t shared_base = o;

  // GAT scratch inside shared region (dead before GRU phase)
  size_t o_deg    = alloc((size_t)NN*4);      // zeroed
  size_t zero_end = o;
  size_t o_tmp    = alloc((size_t)NE*4);
  size_t o_rows   = alloc((size_t)NN*4);
  size_t o_bsum   = alloc(512*4);
  size_t o_rec    = alloc((size_t)NE*16);
  size_t o_sw     = alloc((size_t)NE*8);
  size_t o_m01    = alloc((size_t)NN*8);
  size_t o_as     = alloc((size_t)NN*4);
  size_t o_ad     = alloc((size_t)NN*4);
  size_t o_h      = alloc((size_t)NN*64*2);
  size_t o_xp     = alloc((size_t)NN*64*2);
  size_t gat_end  = o;
  size_t gat_size = gat_end - shared_base;

  const size_t GXC    = (size_t)256*128*384*2;   // 25.17 MB per direction chunk
  const size_t HJK_SZ = (size_t)NN*192*2;        // 48 MB
  size_t shared_sz = gat_size > 4*GXC ? gat_size : 4*GXC;
  size_t o_gx0f = shared_base;               // aliases GAT scratch (dead by GRU phase)
  size_t o_gx0b = shared_base + GXC;
  size_t o_gx1f = shared_base + 2*GXC;
  size_t o_gx1b = shared_base + 3*GXC;
  size_t o_hjk = shared_base + shared_sz;
  size_t o_y   = o_hjk + HJK_SZ;

  int*    deg    = (int*)(ws+o_deg);
  int*    tmp    = (int*)(ws+o_tmp);
  int*    rows   = (int*)(ws+o_rows);
  int*    bsum   = (int*)(ws+o_bsum);
  int4*   rec    = (int4*)(ws+o_rec);
  int2*   sw     = (int2*)(ws+o_sw);
  float2* m01    = (float2*)(ws+o_m01);
  float*  a_s    = (float*)(ws+o_as);
  float*  a_d    = (float*)(ws+o_ad);
  float*  cc     = (float*)(ws+o_cc);
  float*  biasc  = (float*)(ws+o_biasc);
  half_t* h      = (half_t*)(ws+o_h);
  half_t* xp     = (half_t*)(ws+o_xp);
  half_t* hjk    = (half_t*)(ws+o_hjk);
  half_t* BcombT = (half_t*)(ws+o_BcombT);
  half_t* BTgat  = (half_t*)(ws+o_BTgat);
  half_t* W1T    = (half_t*)(ws+o_W1T);
  half_t* whh16  = (half_t*)(ws+o_whh16);
  float*  hstate = (float*)(ws+o_hstate);
  half_t* gxbuf[2][2] = {{(half_t*)(ws+o_gx0f), (half_t*)(ws+o_gx0b)},
                         {(half_t*)(ws+o_gx1f), (half_t*)(ws+o_gx1b)}};
  half_t* y      = (half_t*)(ws+o_y);

  hipMemsetAsync(ws+shared_base, 0, zero_end-shared_base, stream);   // deg
  hipMemsetAsync(ws+o_hstate, 0, (size_t)2*256*128*4, stream);       // GRU h init

  const_kernel<<<3,64,0,stream>>>(gat_We, attE, eW, eb, cc);
  prep_pack<<<1075,256,0,stream>>>(wih_f, wih_b, head_W1, gat_W, bih_f, bih_b, whh_f, whh_b,
                                   BcombT, W1T, BTgat, biasc, whh16);
  bias_fold<<<2,256,0,stream>>>(bhh_f, bhh_b, biasc);
  embed_kernel<<<32768,256,0,stream>>>(x, node_W, node_b, h);
  deg_count<<<4096,256,0,stream>>>(ei, deg, tmp);
  scan1<<<512,256,0,stream>>>(deg, rows, bsum);
  scan2<<<1,512,0,stream>>>(bsum);
  scan3<<<512,256,0,stream>>>(rows, bsum);
  fill2<<<4096,256,0,stream>>>(ei, ea, rows, tmp, rec);
  means_kernel<<<512,256,0,stream>>>(deg, rows, rec, m01);

  for (int l=0;l<3;l++){
    const half_t* in = (l==0)? h : (hjk + (size_t)(l-1)*64);
    int lda = (l==0)? 64 : 192;
    gemm_xp<<<1024,256,0,stream>>>(in, lda, BTgat + (size_t)l*4096, attS + l*64, attD + l*64, xp, a_s, a_d);
    edge_w<<<4096,256,0,stream>>>(rec, a_s, a_d, cc, l, sw);
    agg_lds<<<256,512,0,stream>>>(rows, deg, sw, a_s, a_d, m01, cc, l, xp, gat_b + l*64, hjk);
  }

  // GRU: chunked, with next-chunk gemm fused as extra blocks
  gru_fused<<<1536,512,0,stream>>>(whh16, bhh_f, bhh_b, gxbuf[0][0], gxbuf[0][1], hstate, y, 0, 0,
                                   hjk, BcombT, biasc, gxbuf[0][0], gxbuf[0][1], 0, 384);
  for (int c=0;c<4;c++){
    int buf = c&1, nbuf = (c+1)&1;
    int grid = 32 + (c<3 ? 1536 : 0);
    gru_fused<<<grid,512,0,stream>>>(whh16, bhh_f, bhh_b, gxbuf[buf][0], gxbuf[buf][1], hstate, y, c, 32,
                                     hjk, BcombT, biasc, gxbuf[nbuf][0], gxbuf[nbuf][1],
                                     (c+1)*128, (2-c)*128);
  }

  gemm_head<<<1024,256,0,stream>>>(y, W1T, head_b1, head_W2, head_b2, out);
}

// Round 12
// 1082.934 us; speedup vs baseline: 1.0061x; 1.0061x over previous
//
#include <hip/hip_runtime.h>
#include <cstdint>
#include <cstddef>

typedef _Float16 half_t;
typedef _Float16 half8 __attribute__((ext_vector_type(8)));
typedef float f32x4 __attribute__((ext_vector_type(4)));

constexpr int NN = 131072;    // nodes
constexpr int NE = 1048576;   // edges
constexpr int NPER = 512;

#define DEVINL __device__ __forceinline__

DEVINL float sigm_(float x){ float e = __expf(-x); return __builtin_amdgcn_rcpf(1.f+e); }
DEVINL float tanh_(float x){
  x = fminf(15.f, fmaxf(-15.f, x));
  float e = __expf(-2.f*x);
  return (1.f-e)*__builtin_amdgcn_rcpf(1.f+e);
}

// LDS-only barrier: no vmcnt drain (keeps global loads/stores in flight)
#define LDS_BARRIER() asm volatile("s_waitcnt lgkmcnt(0)\ns_barrier" ::: "memory")

// ---------------- tiny precompute kernels ----------------

__global__ void const_kernel(const float* __restrict__ gatWe,
                             const float* __restrict__ attE, const float* __restrict__ eW,
                             const float* __restrict__ eb, float* __restrict__ cc){
  int l = blockIdx.x, k = threadIdx.x;   // 3 blocks x 64 threads
  const float* Wel = gatWe + l*4096;
  float s3=0.f;
  for (int j=0;j<64;j++) s3 += Wel[k*64+j]*attE[l*64+j];
  float c0 = eW[k]*s3, c1 = eW[64+k]*s3, cb = eb[k]*s3;
  for (int off=1; off<64; off<<=1){
    c0 += __shfl_xor(c0,off); c1 += __shfl_xor(c1,off); cb += __shfl_xor(cb,off);
  }
  if (k==0){ cc[l]=c0; cc[3+l]=c1; cc[6+l]=cb; }
}

// pack/transpose weights to f16
__global__ void prep_pack(const float* __restrict__ wih_f, const float* __restrict__ wih_b,
                          const float* __restrict__ head_W1, const float* __restrict__ gat_W,
                          const float* __restrict__ bih_f, const float* __restrict__ bih_b,
                          const float* __restrict__ whh_f, const float* __restrict__ whh_b,
                          half_t* __restrict__ BcombT, half_t* __restrict__ W1T,
                          half_t* __restrict__ BTgat, float* __restrict__ bias_comb,
                          half_t* __restrict__ whh16){
  int gid = blockIdx.x*256 + threadIdx.x;
  if (gid < 147456){                       // BcombT: j<384 from wih_f else wih_b, k-contig
    int j = gid/192, k = gid%192;
    float v = (j<384)? wih_f[j*192+k] : wih_b[(j-384)*192+k];
    BcombT[gid] = (half_t)v;
  } else if (gid < 163840){                // W1T[n][k] = head_W1[k][n]
    int i = gid - 147456;
    int n = i>>8, k = i&255;
    W1T[i] = (half_t)head_W1[k*64+n];
  } else if (gid < 176128){                // BTgat[l][n][k] = gat_W[l][k][n]
    int i = gid - 163840;
    int l = i>>12, r = i&4095;
    int n = r>>6, k = r&63;
    BTgat[i] = (half_t)gat_W[l*4096 + k*64 + n];
  } else if (gid < 176896){
    int i = gid - 176128;                  // 0..767 (bih; bhh r,z folded by bias_fold)
    int j = (i<384)? i : i-384;
    bias_comb[i] = (i<384)? bih_f[j] : bih_b[j];
  } else if (gid < 275200){                // whh16: flat copy f then b (49152 each)
    int i = gid - 176896;
    float v = (i<49152)? whh_f[i] : whh_b[i-49152];
    whh16[i] = (half_t)v;
  }
}

__global__ void bias_fold(const float* __restrict__ bhh_f, const float* __restrict__ bhh_b,
                          float* __restrict__ bias_comb){
  int i = threadIdx.x + blockIdx.x*256;    // 0..511
  if (i < 256)      bias_comb[i]       += bhh_f[i];
  else if (i < 512) bias_comb[i+128]   += bhh_b[i-256];  // 384..639
}

// ---------------- node embedding ----------------
__global__ __launch_bounds__(256) void embed_kernel(const float* __restrict__ x,
                            const float* __restrict__ nW, const float* __restrict__ nb,
                            half_t* __restrict__ h){
  int gid = blockIdx.x*256 + threadIdx.x;
  int n = gid>>6, j = gid&63;
  float v = x[2*n]*nW[j] + x[2*n+1]*nW[64+j] + nb[j];
  h[(size_t)n*64+j] = (half_t)v;
}

// ---------------- edge preprocessing ----------------
__global__ __launch_bounds__(256) void deg_count(const int* __restrict__ ei,
                          int* __restrict__ deg, int* __restrict__ tmp){
  int e = blockIdx.x*256 + threadIdx.x;
  int dt = ei[NE+e];
  tmp[e] = atomicAdd(&deg[dt],1);
}

__global__ __launch_bounds__(256) void scan1(const int* __restrict__ deg, int* __restrict__ rowstart,
                      int* __restrict__ bsum){
  __shared__ int sc[256];
  int b=blockIdx.x, t=threadIdx.x, i=b*256+t;
  int v=deg[i]; sc[t]=v; __syncthreads();
  for (int off=1; off<256; off<<=1){
    int tv = (t>=off)? sc[t-off] : 0;
    __syncthreads(); sc[t]+=tv; __syncthreads();
  }
  rowstart[i]=sc[t]-v;
  if (t==255) bsum[b]=sc[255];
}
__global__ void scan2(int* __restrict__ bsum){   // 1 block x 512
  __shared__ int sc[512];
  int t=threadIdx.x; int v=bsum[t]; sc[t]=v; __syncthreads();
  for (int off=1; off<512; off<<=1){
    int tv = (t>=off)? sc[t-off] : 0;
    __syncthreads(); sc[t]+=tv; __syncthreads();
  }
  bsum[t]=sc[t]-v;
}
__global__ __launch_bounds__(256) void scan3(int* __restrict__ rowstart, const int* __restrict__ bsum){
  int b=blockIdx.x, t=threadIdx.x, i=b*256+t;
  rowstart[i]+=bsum[b];
}

// one 16B record per edge slot: {src, ea0, ea1, dst}
__global__ __launch_bounds__(256) void fill2(const int* __restrict__ ei, const float* __restrict__ ea,
                      const int* __restrict__ rowstart, const int* __restrict__ tmp,
                      int4* __restrict__ rec){
  int e = blockIdx.x*256 + threadIdx.x;
  int dt = ei[NE+e];
  int slot = rowstart[dt] + tmp[e];
  int4 r;
  r.x = ei[e];
  r.y = __float_as_int(ea[2*e]);
  r.z = __float_as_int(ea[2*e+1]);
  r.w = dt;
  rec[slot] = r;
}

__global__ __launch_bounds__(256) void means_kernel(const int* __restrict__ deg, const int* __restrict__ rowstart,
                         const int4* __restrict__ rec, float2* __restrict__ m01){
  int n = blockIdx.x*256 + threadIdx.x;
  int st = rowstart[n], cnt = deg[n];
  float s0=0.f, s1=0.f;
  for (int i=0;i<cnt;i++){
    int4 r = rec[st+i];
    s0 += __int_as_float(r.y);
    s1 += __int_as_float(r.z);
  }
  float inv = 1.f/(float)max(cnt,1);
  float2 m; m.x = s0*inv; m.y = s1*inv;
  m01[n] = m;
}

// ---------------- xp GEMM with fused attention-logit epilogue ----------------
__global__ __launch_bounds__(256) void gemm_xp(const half_t* __restrict__ A, int lda,
                        const half_t* __restrict__ BT,
                        const float* __restrict__ attS, const float* __restrict__ attD,
                        half_t* __restrict__ xp, float* __restrict__ a_s, float* __restrict__ a_d){
  __shared__ half_t As[128*32];
  __shared__ half_t Bs[64*32];
  const int tid = threadIdx.x, m0 = blockIdx.x*128;
  const int w = tid>>6, lane = tid&63;
  const int lm = lane&15, quad = lane>>4;
  const int wm0 = w*32;
  f32x4 acc[2][4] = {};
  for (int k0=0;k0<64;k0+=32){
    {
      const int c0 = tid*2;
      #pragma unroll
      for (int u=0;u<2;u++){
        int c=c0+u; int row=c>>2; int off=(c&3)*8;
        *(half8*)(&As[row*32+off]) = *(const half8*)(&A[(size_t)(m0+row)*lda + k0 + off]);
      }
      int c=tid; int row=c>>2; int off=(c&3)*8;
      *(half8*)(&Bs[row*32+off]) = *(const half8*)(&BT[(size_t)row*64 + k0 + off]);
    }
    __syncthreads();
    half8 af[2], bf[4];
    #pragma unroll
    for (int nt=0;nt<4;nt++) bf[nt] = *(const half8*)(&Bs[(nt*16+lm)*32 + quad*8]);
    #pragma unroll
    for (int mt=0;mt<2;mt++) af[mt] = *(const half8*)(&As[(wm0+mt*16+lm)*32 + quad*8]);
    #pragma unroll
    for (int mt=0;mt<2;mt++)
      #pragma unroll
      for (int nt=0;nt<4;nt++)
        acc[mt][nt] = __builtin_amdgcn_mfma_f32_16x16x32_f16(af[mt], bf[nt], acc[mt][nt], 0,0,0);
    __syncthreads();
  }
  float vsv[4], vdv[4];
  #pragma unroll
  for (int nt=0;nt<4;nt++){ vsv[nt]=attS[nt*16+lm]; vdv[nt]=attD[nt*16+lm]; }
  #pragma unroll
  for (int mt=0;mt<2;mt++)
   #pragma unroll
   for (int r=0;r<4;r++){
    int m = m0+wm0+mt*16+quad*4+r;
    float ps=0.f, pd=0.f;
    #pragma unroll
    for (int nt=0;nt<4;nt++){
      float v = acc[mt][nt][r];
      xp[(size_t)m*64 + nt*16+lm] = (half_t)v;
      ps += v*vsv[nt]; pd += v*vdv[nt];
    }
    ps += __shfl_xor(ps,1); ps += __shfl_xor(ps,2); ps += __shfl_xor(ps,4); ps += __shfl_xor(ps,8);
    pd += __shfl_xor(pd,1); pd += __shfl_xor(pd,2); pd += __shfl_xor(pd,4); pd += __shfl_xor(pd,8);
    if (lm==0){ a_s[m]=ps; a_d[m]=pd; }
  }
}

// ---------------- slot-parallel edge softmax weight ----------------
__global__ __launch_bounds__(256) void edge_w(const int4* __restrict__ rec,
                       const float* __restrict__ a_s, const float* __restrict__ a_d,
                       const float* __restrict__ cc, int l, int2* __restrict__ sw){
  int s = blockIdx.x*256 + threadIdx.x;
  int4 r = rec[s];
  float al = a_s[r.x] + a_d[r.w]
           + __int_as_float(r.y)*cc[l] + __int_as_float(r.z)*cc[3+l] + cc[6+l];
  al = al>0.f? al : 0.2f*al;
  int2 o; o.x = r.x; o.y = __float_as_int(__expf(al));
  sw[s] = o;
}

// ---------------- graph-local LDS aggregate, 4 blocks/graph, pipelined ----------------
// blockIdx = g*4+sub. Stage full xp[g] window (64KB) into LDS; block handles 128 nodes;
// each wave walks 16 nodes. ds_read for edge k+1 issued one iteration early.
__global__ __launch_bounds__(512,4) void agg_lds(const int* __restrict__ rowstart, const int* __restrict__ deg,
                          const int2* __restrict__ sw,
                          const float* __restrict__ a_s, const float* __restrict__ a_d,
                          const float2* __restrict__ m01, const float* __restrict__ cc, int l,
                          const half_t* __restrict__ xp, const float* __restrict__ bias,
                          half_t* __restrict__ hjk){
  __shared__ half_t xs[512*64];   // 64 KB
  const int g = blockIdx.x >> 2;
  const int sub = blockIdx.x & 3;
  const int tid = threadIdx.x;
  {
    const half8* srcp = (const half8*)(xp + (size_t)g*32768);
    half8* dstp = (half8*)xs;
    #pragma unroll
    for (int i=0;i<8;i++)
      dstp[tid + i*512] = srcp[tid + i*512];
  }
  __syncthreads();
  const int w = tid>>6, lane = tid&63;
  const float bv = bias[lane];
  const float c0=cc[l], c1=cc[3+l], cb=cc[6+l];
  const int nbase = g*512 + sub*128 + w*16;
  for (int i=0;i<16;i++){
    int n = nbase + i;
    int st = rowstart[n], cnt = deg[n];
    float acc=0.f, den=0.f;
    if (cnt>0){
      int2 p = sw[st];
      float xv = (float)xs[(p.x&511)*64 + lane];
      for (int k=0;k<cnt;k++){
        int2 pn; float xvn=0.f;
        if (k+1<cnt){
          pn = sw[st+k+1];
          xvn = (float)xs[(pn.x&511)*64 + lane];   // issued a full iter early
        }
        float ww = __int_as_float(p.y);
        den += ww;
        acc += ww*xv;
        p = pn; xv = xvn;
      }
    }
    float2 m = m01[n];
    float ael = cnt? (m.x*c0 + m.y*c1 + cb) : 0.f;
    float asl = a_s[n] + a_d[n] + ael;
    asl = asl>0.f? asl : 0.2f*asl;
    float wsf = __expf(asl);
    den += wsf;
    acc += wsf*(float)xs[(n&511)*64 + lane];
    float v = acc/den + bv;
    v = v>0.f? v : 0.01f*v;
    hjk[(size_t)n*192 + l*64 + lane] = (half_t)v;
  }
}

// ---------------- head GEMM with fused MLP-2 epilogue ----------------
__global__ __launch_bounds__(256) void gemm_head(const half_t* __restrict__ A,
                        const half_t* __restrict__ W1T, const float* __restrict__ b1,
                        const float* __restrict__ W2, const float* __restrict__ b2,
                        float* __restrict__ out){
  __shared__ half_t As[128*32];
  __shared__ half_t Bs[64*32];
  const int tid = threadIdx.x, m0 = blockIdx.x*128;
  const int w = tid>>6, lane = tid&63;
  const int lm = lane&15, quad = lane>>4;
  const int wm0 = w*32;
  f32x4 acc[2][4] = {};
  for (int k0=0;k0<256;k0+=32){
    {
      const int c0 = tid*2;
      #pragma unroll
      for (int u=0;u<2;u++){
        int c=c0+u; int row=c>>2; int off=(c&3)*8;
        *(half8*)(&As[row*32+off]) = *(const half8*)(&A[(size_t)(m0+row)*256 + k0 + off]);
      }
      int c=tid; int row=c>>2; int off=(c&3)*8;
      *(half8*)(&Bs[row*32+off]) = *(const half8*)(&W1T[(size_t)row*256 + k0 + off]);
    }
    __syncthreads();
    half8 af[2], bf[4];
    #pragma unroll
    for (int nt=0;nt<4;nt++) bf[nt] = *(const half8*)(&Bs[(nt*16+lm)*32 + quad*8]);
    #pragma unroll
    for (int mt=0;mt<2;mt++) af[mt] = *(const half8*)(&As[(wm0+mt*16+lm)*32 + quad*8]);
    #pragma unroll
    for (int mt=0;mt<2;mt++)
      #pragma unroll
      for (int nt=0;nt<4;nt++)
        acc[mt][nt] = __builtin_amdgcn_mfma_f32_16x16x32_f16(af[mt], bf[nt], acc[mt][nt], 0,0,0);
    __syncthreads();
  }
  float b1v[4], w20[4], w21[4];
  #pragma unroll
  for (int nt=0;nt<4;nt++){
    int n = nt*16+lm;
    b1v[nt]=b1[n]; w20[nt]=W2[n*2]; w21[nt]=W2[n*2+1];
  }
  float b20=b2[0], b21=b2[1];
  #pragma unroll
  for (int mt=0;mt<2;mt++)
   #pragma unroll
   for (int r=0;r<4;r++){
    int m = m0+wm0+mt*16+quad*4+r;
    float p0=0.f, p1=0.f;
    #pragma unroll
    for (int nt=0;nt<4;nt++){
      float v = acc[mt][nt][r] + b1v[nt];
      v = v>0.f? v : 0.f;
      p0 += v*w20[nt]; p1 += v*w21[nt];
    }
    p0 += __shfl_xor(p0,1); p0 += __shfl_xor(p0,2); p0 += __shfl_xor(p0,4); p0 += __shfl_xor(p0,8);
    p1 += __shfl_xor(p1,1); p1 += __shfl_xor(p1,2); p1 += __shfl_xor(p1,4); p1 += __shfl_xor(p1,8);
    if (lm==0){
      out[(size_t)m*2]   = p0 + b20;
      out[(size_t)m*2+1] = p1 + b21;
    }
  }
}

// ---------------- fused GRU recurrence + next-chunk gx GEMM ----------------
__global__ __launch_bounds__(512,1) void gru_fused(
    const half_t* __restrict__ whh16, const float* __restrict__ bhh_f, const float* __restrict__ bhh_b,
    const half_t* __restrict__ gxf, const half_t* __restrict__ gxb,
    float* __restrict__ hstate, half_t* __restrict__ y, int c, int gruBlocks,
    const half_t* __restrict__ hjk, const half_t* __restrict__ BcombT, const float* __restrict__ biasc,
    half_t* __restrict__ gxf_n, half_t* __restrict__ gxb_n, int s0f, int s0b){
  __shared__ half_t h16[2][16][132];
  __shared__ half_t As[128*32];
  __shared__ half_t Bs[128*32];
  const int bid = blockIdx.x;
  const int tid = threadIdx.x;
  if (bid < gruBlocks){
    // ---------------- GRU path ----------------
    const int d = bid >> 4, gblk = bid & 15;
    const half_t* __restrict__ gx = d ? gxb : gxf;
    const float* bhh = d ? bhh_b : bhh_f;
    const int w = tid >> 6, lane = tid & 63;
    const int l15 = lane & 15, quad = lane >> 4;
    const int unit = w*16 + l15;

    half8 bf[3][4];
    float bhn = bhh[256 + unit];
    {
      const half_t* wbase = whh16 + (size_t)d*49152;
      #pragma unroll
      for (int g=0; g<3; g++){
        const half_t* wp = wbase + (size_t)(g*128 + unit)*128;
        #pragma unroll
        for (int kk=0; kk<4; kk++)
          bf[g][kk] = *(const half8*)(wp + kk*32 + quad*8);
      }
    }

    float hreg[4];
    #pragma unroll
    for (int r=0;r<4;r++)
      hreg[r] = hstate[((size_t)d*256 + gblk*16 + quad*4 + r)*128 + unit];
    #pragma unroll
    for (int r=0;r<4;r++)
      h16[0][quad*4+r][unit] = (half_t)hreg[r];

    const int jstep = d ? -384 : 384;
    const int ystep = d ? -256 : 256;
    const int j0 = d ? 127 : 0;
    const int pos0 = d ? (511 - c*128) : (c*128);
    const int gr = gblk*16 + quad*4;
    int gvo[4], yvo[4];
    #pragma unroll
    for (int r=0;r<4;r++){
      gvo[r] = ((gr+r)*128 + j0)*384 + unit;
      yvo[r] = ((gr+r)*512 + pos0)*256 + d*128 + unit;
    }

    half_t gva[12], gvb[12];
    #pragma unroll
    for (int g=0;g<3;g++)
      #pragma unroll
      for (int r=0;r<4;r++) gva[g*4+r] = gx[gvo[r] + g*128];
    #pragma unroll
    for (int r=0;r<4;r++) gvo[r] += jstep;
    LDS_BARRIER();

    auto step = [&](int rd, int wr, half_t* gc, half_t* gn, bool pf){
      if (pf){
        #pragma unroll
        for (int g=0;g<3;g++)
          #pragma unroll
          for (int r=0;r<4;r++) gn[g*4+r] = gx[gvo[r] + g*128];
        #pragma unroll
        for (int r=0;r<4;r++) gvo[r] += jstep;
      }
      half8 af[4];
      #pragma unroll
      for (int kk=0;kk<4;kk++)
        af[kk] = *(const half8*)(&h16[rd][l15][kk*32 + quad*8]);
      f32x4 P[3] = {};
      #pragma unroll
      for (int kk=0;kk<4;kk++)
        #pragma unroll
        for (int g=0;g<3;g++)
          P[g] = __builtin_amdgcn_mfma_f32_16x16x32_f16(af[kk], bf[g][kk], P[g], 0,0,0);
      #pragma unroll
      for (int r=0;r<4;r++){
        float rr = sigm_((float)gc[0*4+r] + P[0][r]);
        float zz = sigm_((float)gc[1*4+r] + P[1][r]);
        float nn = tanh_((float)gc[2*4+r] + rr*(P[2][r] + bhn));
        float hn = nn + zz*(hreg[r]-nn);
        hreg[r] = hn;
        h16[wr][quad*4+r][unit] = (half_t)hn;
        y[yvo[r]] = (half_t)hn;
        yvo[r] += ystep;
      }
      LDS_BARRIER();
    };
    for (int it=0; it<63; it++){
      step(0,1,gva,gvb,true);
      step(1,0,gvb,gva,true);
    }
    step(0,1,gva,gvb,true);
    step(1,0,gvb,gva,false);
    #pragma unroll
    for (int r=0;r<4;r++)
      hstate[((size_t)d*256 + gblk*16 + quad*4 + r)*128 + unit] = hreg[r];
  } else {
    // ---------------- gemm path (512 threads, 8 waves) ----------------
    const int gb = bid - gruBlocks;
    const int bx = gb & 255, by = gb >> 8;       // 256 x 6
    const int m0 = bx*128;
    const bool back = by >= 3;
    const int n0 = (back ? by-3 : by)*128;
    const int step0 = back ? s0b : s0f;
    half_t* C = back ? gxb_n : gxf_n;
    const half_t* BTh = BcombT + (back ? (size_t)384*192 : 0);
    const float* bh = biasc + (back ? 384 : 0);
    const int w = tid>>6, lane = tid&63;
    const int lm = lane&15, quad = lane>>4;
    const int wm0 = (w>>2)*64, wn0 = (w&3)*32;
    f32x4 acc[4][2] = {};
    for (int k0=0; k0<192; k0+=32){
      {
        int cidx = tid; int row = cidx>>2; int off = (cidx&3)*8;
        int m = m0+row;
        size_t arow = (size_t)(m>>7)*512 + step0 + (m&127);
        *(half8*)(&As[row*32+off]) = *(const half8*)(&hjk[arow*192 + k0 + off]);
        *(half8*)(&Bs[row*32+off]) = *(const half8*)(&BTh[(size_t)(n0+row)*192 + k0 + off]);
      }
      __syncthreads();
      half8 af[4], bfr[2];
      #pragma unroll
      for (int nt=0;nt<2;nt++) bfr[nt] = *(const half8*)(&Bs[(wn0+nt*16+lm)*32 + quad*8]);
      #pragma unroll
      for (int mt=0;mt<4;mt++) af[mt] = *(const half8*)(&As[(wm0+mt*16+lm)*32 + quad*8]);
      #pragma unroll
      for (int mt=0;mt<4;mt++)
        #pragma unroll
        for (int nt=0;nt<2;nt++)
          acc[mt][nt] = __builtin_amdgcn_mfma_f32_16x16x32_f16(af[mt], bfr[nt], acc[mt][nt], 0,0,0);
      __syncthreads();
    }
    #pragma unroll
    for (int mt=0;mt<4;mt++)
     #pragma unroll
     for (int nt=0;nt<2;nt++)
      #pragma unroll
      for (int r=0;r<4;r++){
        int m = m0+wm0+mt*16+quad*4+r;
        int n = n0+wn0+nt*16+lm;
        float v = acc[mt][nt][r] + bh[n];
        C[(size_t)m*384 + n] = (half_t)v;
      }
  }
}

// ---------------- launch ----------------
extern "C" void kernel_launch(void* const* d_in, const int* in_sizes, int n_in,
                              void* d_out, int out_size, void* d_ws, size_t ws_size,
                              hipStream_t stream) {
  const float* x       = (const float*)d_in[0];
  const float* ea      = (const float*)d_in[1];
  const float* node_W  = (const float*)d_in[2];
  const float* node_b  = (const float*)d_in[3];
  const float* eW      = (const float*)d_in[4];
  const float* eb      = (const float*)d_in[5];
  const float* gat_W   = (const float*)d_in[6];
  const float* gat_We  = (const float*)d_in[7];
  const float* attS    = (const float*)d_in[8];
  const float* attD    = (const float*)d_in[9];
  const float* attE    = (const float*)d_in[10];
  const float* gat_b   = (const float*)d_in[11];
  const float* wih_f   = (const float*)d_in[12];
  const float* whh_f   = (const float*)d_in[13];
  const float* bih_f   = (const float*)d_in[14];
  const float* bhh_f   = (const float*)d_in[15];
  const float* wih_b   = (const float*)d_in[16];
  const float* whh_b   = (const float*)d_in[17];
  const float* bih_b   = (const float*)d_in[18];
  const float* bhh_b   = (const float*)d_in[19];
  const float* head_W1 = (const float*)d_in[20];
  const float* head_b1 = (const float*)d_in[21];
  const float* head_W2 = (const float*)d_in[22];
  const float* head_b2 = (const float*)d_in[23];
  const int*   ei      = (const int*)d_in[24];
  float* out = (float*)d_out;
  char* ws = (char*)d_ws;
  (void)in_sizes; (void)n_in; (void)out_size; (void)ws_size;

  size_t o = 0;
  auto alloc = [&](size_t bytes)->size_t{ size_t r=o; o += (bytes+255)&~(size_t)255; return r; };
  // persistent region
  size_t o_cc     = alloc(16*4);
  size_t o_biasc  = alloc(768*4);
  size_t o_BcombT = alloc((size_t)768*192*2);
  size_t o_BTgat  = alloc((size_t)3*4096*2);
  size_t o_W1T    = alloc((size_t)64*256*2);
  size_t o_whh16  = alloc((size_t)2*49152*2);
  size_t o_hstate = alloc((size_t)2*256*128*4);
  size_t shared_base = o;

  // GAT scratch inside shared region (dead before GRU phase)
  size_t o_deg    = alloc((size_t)NN*4);      // zeroed
  size_t zero_end = o;
  size_t o_tmp    = alloc((size_t)NE*4);
  size_t o_rows   = alloc((size_t)NN*4);
  size_t o_bsum   = alloc(512*4);
  size_t o_rec    = alloc((size_t)NE*16);
  size_t o_sw     = alloc((size_t)NE*8);
  size_t o_m01    = alloc((size_t)NN*8);
  size_t o_as     = alloc((size_t)NN*4);
  size_t o_ad     = alloc((size_t)NN*4);
  size_t o_h      = alloc((size_t)NN*64*2);
  size_t o_xp     = alloc((size_t)NN*64*2);
  size_t gat_end  = o;
  size_t gat_size = gat_end - shared_base;

  const size_t GXC    = (size_t)256*128*384*2;   // 25.17 MB per direction chunk
  const size_t HJK_SZ = (size_t)NN*192*2;        // 48 MB
  size_t shared_sz = gat_size > 4*GXC ? gat_size : 4*GXC;
  size_t o_gx0f = shared_base;               // aliases GAT scratch (dead by GRU phase)
  size_t o_gx0b = shared_base + GXC;
  size_t o_gx1f = shared_base + 2*GXC;
  size_t o_gx1b = shared_base + 3*GXC;
  size_t o_hjk = shared_base + shared_sz;
  size_t o_y   = o_hjk + HJK_SZ;

  int*    deg    = (int*)(ws+o_deg);
  int*    tmp    = (int*)(ws+o_tmp);
  int*    rows   = (int*)(ws+o_rows);
  int*    bsum   = (int*)(ws+o_bsum);
  int4*   rec    = (int4*)(ws+o_rec);
  int2*   sw     = (int2*)(ws+o_sw);
  float2* m01    = (float2*)(ws+o_m01);
  float*  a_s    = (float*)(ws+o_as);
  float*  a_d    = (float*)(ws+o_ad);
  float*  cc     = (float*)(ws+o_cc);
  float*  biasc  = (float*)(ws+o_biasc);
  half_t* h      = (half_t*)(ws+o_h);
  half_t* xp     = (half_t*)(ws+o_xp);
  half_t* hjk    = (half_t*)(ws+o_hjk);
  half_t* BcombT = (half_t*)(ws+o_BcombT);
  half_t* BTgat  = (half_t*)(ws+o_BTgat);
  half_t* W1T    = (half_t*)(ws+o_W1T);
  half_t* whh16  = (half_t*)(ws+o_whh16);
  float*  hstate = (float*)(ws+o_hstate);
  half_t* gxbuf[2][2] = {{(half_t*)(ws+o_gx0f), (half_t*)(ws+o_gx0b)},
                         {(half_t*)(ws+o_gx1f), (half_t*)(ws+o_gx1b)}};
  half_t* y      = (half_t*)(ws+o_y);

  hipMemsetAsync(ws+shared_base, 0, zero_end-shared_base, stream);   // deg
  hipMemsetAsync(ws+o_hstate, 0, (size_t)2*256*128*4, stream);       // GRU h init

  const_kernel<<<3,64,0,stream>>>(gat_We, attE, eW, eb, cc);
  prep_pack<<<1075,256,0,stream>>>(wih_f, wih_b, head_W1, gat_W, bih_f, bih_b, whh_f, whh_b,
                                   BcombT, W1T, BTgat, biasc, whh16);
  bias_fold<<<2,256,0,stream>>>(bhh_f, bhh_b, biasc);
  embed_kernel<<<32768,256,0,stream>>>(x, node_W, node_b, h);
  deg_count<<<4096,256,0,stream>>>(ei, deg, tmp);
  scan1<<<512,256,0,stream>>>(deg, rows, bsum);
  scan2<<<1,512,0,stream>>>(bsum);
  scan3<<<512,256,0,stream>>>(rows, bsum);
  fill2<<<4096,256,0,stream>>>(ei, ea, rows, tmp, rec);
  means_kernel<<<512,256,0,stream>>>(deg, rows, rec, m01);

  for (int l=0;l<3;l++){
    const half_t* in = (l==0)? h : (hjk + (size_t)(l-1)*64);
    int lda = (l==0)? 64 : 192;
    gemm_xp<<<1024,256,0,stream>>>(in, lda, BTgat + (size_t)l*4096, attS + l*64, attD + l*64, xp, a_s, a_d);
    edge_w<<<4096,256,0,stream>>>(rec, a_s, a_d, cc, l, sw);
    agg_lds<<<1024,512,0,stream>>>(rows, deg, sw, a_s, a_d, m01, cc, l, xp, gat_b + l*64, hjk);
  }

  // GRU: chunked, with next-chunk gemm fused as extra blocks
  gru_fused<<<1536,512,0,stream>>>(whh16, bhh_f, bhh_b, gxbuf[0][0], gxbuf[0][1], hstate, y, 0, 0,
                                   hjk, BcombT, biasc, gxbuf[0][0], gxbuf[0][1], 0, 384);
  for (int c=0;c<4;c++){
    int buf = c&1, nbuf = (c+1)&1;
    int grid = 32 + (c<3 ? 1536 : 0);
    gru_fused<<<grid,512,0,stream>>>(whh16, bhh_f, bhh_b, gxbuf[buf][0], gxbuf[buf][1], hstate, y, c, 32,
                                     hjk, BcombT, biasc, gxbuf[nbuf][0], gxbuf[nbuf][1],
                                     (c+1)*128, (2-c)*128);
  }

  gemm_head<<<1024,256,0,stream>>>(y, W1T, head_b1, head_W2, head_b2, out);
}

// Round 13
// 974.710 us; speedup vs baseline: 1.1178x; 1.1110x over previous
//
#include <hip/hip_runtime.h>
#include <cstdint>
#include <cstddef>

typedef _Float16 half_t;
typedef _Float16 half8 __attribute__((ext_vector_type(8)));
typedef float f32x4 __attribute__((ext_vector_type(4)));

constexpr int NN = 131072;    // nodes
constexpr int NE = 1048576;   // edges
constexpr int NPER = 512;

#define DEVINL __device__ __forceinline__

DEVINL float sigm_(float x){ float e = __expf(-x); return __builtin_amdgcn_rcpf(1.f+e); }
DEVINL float tanh_(float x){
  x = fminf(15.f, fmaxf(-15.f, x));
  float e = __expf(-2.f*x);
  return (1.f-e)*__builtin_amdgcn_rcpf(1.f+e);
}

// LDS-only barrier: no vmcnt drain (keeps global loads/stores in flight)
#define LDS_BARRIER() asm volatile("s_waitcnt lgkmcnt(0)\ns_barrier" ::: "memory")

// ---------------- tiny precompute kernels ----------------

__global__ void const_kernel(const float* __restrict__ gatWe,
                             const float* __restrict__ attE, const float* __restrict__ eW,
                             const float* __restrict__ eb, float* __restrict__ cc){
  int l = blockIdx.x, k = threadIdx.x;   // 3 blocks x 64 threads
  const float* Wel = gatWe + l*4096;
  float s3=0.f;
  for (int j=0;j<64;j++) s3 += Wel[k*64+j]*attE[l*64+j];
  float c0 = eW[k]*s3, c1 = eW[64+k]*s3, cb = eb[k]*s3;
  for (int off=1; off<64; off<<=1){
    c0 += __shfl_xor(c0,off); c1 += __shfl_xor(c1,off); cb += __shfl_xor(cb,off);
  }
  if (k==0){ cc[l]=c0; cc[3+l]=c1; cc[6+l]=cb; }
}

// pack/transpose weights to f16
__global__ void prep_pack(const float* __restrict__ wih_f, const float* __restrict__ wih_b,
                          const float* __restrict__ head_W1, const float* __restrict__ gat_W,
                          const float* __restrict__ bih_f, const float* __restrict__ bih_b,
                          const float* __restrict__ whh_f, const float* __restrict__ whh_b,
                          half_t* __restrict__ BcombT, half_t* __restrict__ W1T,
                          half_t* __restrict__ BTgat, float* __restrict__ bias_comb,
                          half_t* __restrict__ whh16){
  int gid = blockIdx.x*256 + threadIdx.x;
  if (gid < 147456){                       // BcombT: j<384 from wih_f else wih_b, k-contig
    int j = gid/192, k = gid%192;
    float v = (j<384)? wih_f[j*192+k] : wih_b[(j-384)*192+k];
    BcombT[gid] = (half_t)v;
  } else if (gid < 163840){                // W1T[n][k] = head_W1[k][n]
    int i = gid - 147456;
    int n = i>>8, k = i&255;
    W1T[i] = (half_t)head_W1[k*64+n];
  } else if (gid < 176128){                // BTgat[l][n][k] = gat_W[l][k][n]
    int i = gid - 163840;
    int l = i>>12, r = i&4095;
    int n = r>>6, k = r&63;
    BTgat[i] = (half_t)gat_W[l*4096 + k*64 + n];
  } else if (gid < 176896){
    int i = gid - 176128;                  // 0..767 (bih; bhh r,z folded by bias_fold)
    int j = (i<384)? i : i-384;
    bias_comb[i] = (i<384)? bih_f[j] : bih_b[j];
  } else if (gid < 275200){                // whh16: flat copy f then b (49152 each)
    int i = gid - 176896;
    float v = (i<49152)? whh_f[i] : whh_b[i-49152];
    whh16[i] = (half_t)v;
  }
}

__global__ void bias_fold(const float* __restrict__ bhh_f, const float* __restrict__ bhh_b,
                          float* __restrict__ bias_comb){
  int i = threadIdx.x + blockIdx.x*256;    // 0..511
  if (i < 256)      bias_comb[i]       += bhh_f[i];
  else if (i < 512) bias_comb[i+128]   += bhh_b[i-256];  // 384..639
}

// ---------------- node embedding ----------------
__global__ __launch_bounds__(256) void embed_kernel(const float* __restrict__ x,
                            const float* __restrict__ nW, const float* __restrict__ nb,
                            half_t* __restrict__ h){
  int gid = blockIdx.x*256 + threadIdx.x;
  int n = gid>>6, j = gid&63;
  float v = x[2*n]*nW[j] + x[2*n+1]*nW[64+j] + nb[j];
  h[(size_t)n*64+j] = (half_t)v;
}

// ---------------- edge preprocessing ----------------
__global__ __launch_bounds__(256) void deg_count(const int* __restrict__ ei,
                          int* __restrict__ deg, int* __restrict__ tmp){
  int e = blockIdx.x*256 + threadIdx.x;
  int dt = ei[NE+e];
  tmp[e] = atomicAdd(&deg[dt],1);
}

__global__ __launch_bounds__(256) void scan1(const int* __restrict__ deg, int* __restrict__ rowstart,
                      int* __restrict__ bsum){
  __shared__ int sc[256];
  int b=blockIdx.x, t=threadIdx.x, i=b*256+t;
  int v=deg[i]; sc[t]=v; __syncthreads();
  for (int off=1; off<256; off<<=1){
    int tv = (t>=off)? sc[t-off] : 0;
    __syncthreads(); sc[t]+=tv; __syncthreads();
  }
  rowstart[i]=sc[t]-v;
  if (t==255) bsum[b]=sc[255];
}
__global__ void scan2(int* __restrict__ bsum){   // 1 block x 512
  __shared__ int sc[512];
  int t=threadIdx.x; int v=bsum[t]; sc[t]=v; __syncthreads();
  for (int off=1; off<512; off<<=1){
    int tv = (t>=off)? sc[t-off] : 0;
    __syncthreads(); sc[t]+=tv; __syncthreads();
  }
  bsum[t]=sc[t]-v;
}
__global__ __launch_bounds__(256) void scan3(int* __restrict__ rowstart, const int* __restrict__ bsum){
  int b=blockIdx.x, t=threadIdx.x, i=b*256+t;
  rowstart[i]+=bsum[b];
}

// one 16B record per edge slot: {src, ea0, ea1, dst}
__global__ __launch_bounds__(256) void fill2(const int* __restrict__ ei, const float* __restrict__ ea,
                      const int* __restrict__ rowstart, const int* __restrict__ tmp,
                      int4* __restrict__ rec){
  int e = blockIdx.x*256 + threadIdx.x;
  int dt = ei[NE+e];
  int slot = rowstart[dt] + tmp[e];
  int4 r;
  r.x = ei[e];
  r.y = __float_as_int(ea[2*e]);
  r.z = __float_as_int(ea[2*e+1]);
  r.w = dt;
  rec[slot] = r;
}

__global__ __launch_bounds__(256) void means_kernel(const int* __restrict__ deg, const int* __restrict__ rowstart,
                         const int4* __restrict__ rec, float2* __restrict__ m01){
  int n = blockIdx.x*256 + threadIdx.x;
  int st = rowstart[n], cnt = deg[n];
  float s0=0.f, s1=0.f;
  for (int i=0;i<cnt;i++){
    int4 r = rec[st+i];
    s0 += __int_as_float(r.y);
    s1 += __int_as_float(r.z);
  }
  float inv = 1.f/(float)max(cnt,1);
  float2 m; m.x = s0*inv; m.y = s1*inv;
  m01[n] = m;
}

// ---------------- xp GEMM with fused attention-logit epilogue ----------------
__global__ __launch_bounds__(256) void gemm_xp(const half_t* __restrict__ A, int lda,
                        const half_t* __restrict__ BT,
                        const float* __restrict__ attS, const float* __restrict__ attD,
                        half_t* __restrict__ xp, float* __restrict__ a_s, float* __restrict__ a_d){
  __shared__ half_t As[128*32];
  __shared__ half_t Bs[64*32];
  const int tid = threadIdx.x, m0 = blockIdx.x*128;
  const int w = tid>>6, lane = tid&63;
  const int lm = lane&15, quad = lane>>4;
  const int wm0 = w*32;
  f32x4 acc[2][4] = {};
  for (int k0=0;k0<64;k0+=32){
    {
      const int c0 = tid*2;
      #pragma unroll
      for (int u=0;u<2;u++){
        int c=c0+u; int row=c>>2; int off=(c&3)*8;
        *(half8*)(&As[row*32+off]) = *(const half8*)(&A[(size_t)(m0+row)*lda + k0 + off]);
      }
      int c=tid; int row=c>>2; int off=(c&3)*8;
      *(half8*)(&Bs[row*32+off]) = *(const half8*)(&BT[(size_t)row*64 + k0 + off]);
    }
    __syncthreads();
    half8 af[2], bf[4];
    #pragma unroll
    for (int nt=0;nt<4;nt++) bf[nt] = *(const half8*)(&Bs[(nt*16+lm)*32 + quad*8]);
    #pragma unroll
    for (int mt=0;mt<2;mt++) af[mt] = *(const half8*)(&As[(wm0+mt*16+lm)*32 + quad*8]);
    #pragma unroll
    for (int mt=0;mt<2;mt++)
      #pragma unroll
      for (int nt=0;nt<4;nt++)
        acc[mt][nt] = __builtin_amdgcn_mfma_f32_16x16x32_f16(af[mt], bf[nt], acc[mt][nt], 0,0,0);
    __syncthreads();
  }
  float vsv[4], vdv[4];
  #pragma unroll
  for (int nt=0;nt<4;nt++){ vsv[nt]=attS[nt*16+lm]; vdv[nt]=attD[nt*16+lm]; }
  #pragma unroll
  for (int mt=0;mt<2;mt++)
   #pragma unroll
   for (int r=0;r<4;r++){
    int m = m0+wm0+mt*16+quad*4+r;
    float ps=0.f, pd=0.f;
    #pragma unroll
    for (int nt=0;nt<4;nt++){
      float v = acc[mt][nt][r];
      xp[(size_t)m*64 + nt*16+lm] = (half_t)v;
      ps += v*vsv[nt]; pd += v*vdv[nt];
    }
    ps += __shfl_xor(ps,1); ps += __shfl_xor(ps,2); ps += __shfl_xor(ps,4); ps += __shfl_xor(ps,8);
    pd += __shfl_xor(pd,1); pd += __shfl_xor(pd,2); pd += __shfl_xor(pd,4); pd += __shfl_xor(pd,8);
    if (lm==0){ a_s[m]=ps; a_d[m]=pd; }
  }
}

// ---------------- slot-parallel edge softmax weight ----------------
__global__ __launch_bounds__(256) void edge_w(const int4* __restrict__ rec,
                       const float* __restrict__ a_s, const float* __restrict__ a_d,
                       const float* __restrict__ cc, int l, int2* __restrict__ sw){
  int s = blockIdx.x*256 + threadIdx.x;
  int4 r = rec[s];
  float al = a_s[r.x] + a_d[r.w]
           + __int_as_float(r.y)*cc[l] + __int_as_float(r.z)*cc[3+l] + cc[6+l];
  al = al>0.f? al : 0.2f*al;
  int2 o; o.x = r.x; o.y = __float_as_int(__expf(al));
  sw[s] = o;
}

// ---------------- graph-local LDS aggregate: xs + sw segment both in LDS ----------------
// blockIdx = g*4+sub. Stage xp[g] window (64KB) + the block's contiguous sw slot
// segment (<=1536 entries, 12KB) into LDS. Inner loop is pure LDS->LDS.
constexpr int SWCAP = 1536;
__global__ __launch_bounds__(512,4) void agg_lds(const int* __restrict__ rowstart, const int* __restrict__ deg,
                          const int2* __restrict__ sw,
                          const float* __restrict__ a_s, const float* __restrict__ a_d,
                          const float2* __restrict__ m01, const float* __restrict__ cc, int l,
                          const half_t* __restrict__ xp, const float* __restrict__ bias,
                          half_t* __restrict__ hjk){
  __shared__ half_t xs[512*64];   // 64 KB
  __shared__ int2  swl[SWCAP];    // 12 KB
  const int g = blockIdx.x >> 2;
  const int sub = blockIdx.x & 3;
  const int tid = threadIdx.x;
  const int nbase = g*512 + sub*128;
  const int segst = rowstart[nbase];
  const int segend = rowstart[nbase+127] + deg[nbase+127];
  const int segcnt = segend - segst;
  {
    const half8* srcp = (const half8*)(xp + (size_t)g*32768);
    half8* dstp = (half8*)xs;
    #pragma unroll
    for (int i=0;i<8;i++)
      dstp[tid + i*512] = srcp[tid + i*512];
    int scap = segcnt < SWCAP ? segcnt : SWCAP;
    for (int i=tid; i<scap; i+=512)
      swl[i] = sw[segst+i];
  }
  __syncthreads();
  const int w = tid>>6, lane = tid&63;
  const float bv = bias[lane];
  const float c0=cc[l], c1=cc[3+l], cb=cc[6+l];
  const int nb2 = nbase + w*16;
  for (int i=0;i<16;i++){
    int n = nb2 + i;
    int st = rowstart[n] - segst, cnt = deg[n];
    float acc=0.f, den=0.f;
    if (cnt>0){
      if (st + cnt <= SWCAP){
        // fast path: sw stream from LDS
        int2 p = swl[st];
        float xv = (float)xs[(p.x&511)*64 + lane];
        for (int k=0;k<cnt;k++){
          int2 pn; float xvn=0.f;
          if (k+1<cnt){
            pn = swl[st+k+1];
            xvn = (float)xs[(pn.x&511)*64 + lane];
          }
          float ww = __int_as_float(p.y);
          den += ww;
          acc += ww*xv;
          p = pn; xv = xvn;
        }
      } else {
        // overflow path (wave-uniform, essentially never taken)
        int2 p = sw[segst+st];
        float xv = (float)xs[(p.x&511)*64 + lane];
        for (int k=0;k<cnt;k++){
          int2 pn; float xvn=0.f;
          if (k+1<cnt){
            pn = sw[segst+st+k+1];
            xvn = (float)xs[(pn.x&511)*64 + lane];
          }
          float ww = __int_as_float(p.y);
          den += ww;
          acc += ww*xv;
          p = pn; xv = xvn;
        }
      }
    }
    float2 m = m01[n];
    float ael = cnt? (m.x*c0 + m.y*c1 + cb) : 0.f;
    float asl = a_s[n] + a_d[n] + ael;
    asl = asl>0.f? asl : 0.2f*asl;
    float wsf = __expf(asl);
    den += wsf;
    acc += wsf*(float)xs[(n&511)*64 + lane];
    float v = acc/den + bv;
    v = v>0.f? v : 0.01f*v;
    hjk[(size_t)n*192 + l*64 + lane] = (half_t)v;
  }
}

// ---------------- head GEMM with fused MLP-2 epilogue ----------------
__global__ __launch_bounds__(256) void gemm_head(const half_t* __restrict__ A,
                        const half_t* __restrict__ W1T, const float* __restrict__ b1,
                        const float* __restrict__ W2, const float* __restrict__ b2,
                        float* __restrict__ out){
  __shared__ half_t As[128*32];
  __shared__ half_t Bs[64*32];
  const int tid = threadIdx.x, m0 = blockIdx.x*128;
  const int w = tid>>6, lane = tid&63;
  const int lm = lane&15, quad = lane>>4;
  const int wm0 = w*32;
  f32x4 acc[2][4] = {};
  for (int k0=0;k0<256;k0+=32){
    {
      const int c0 = tid*2;
      #pragma unroll
      for (int u=0;u<2;u++){
        int c=c0+u; int row=c>>2; int off=(c&3)*8;
        *(half8*)(&As[row*32+off]) = *(const half8*)(&A[(size_t)(m0+row)*256 + k0 + off]);
      }
      int c=tid; int row=c>>2; int off=(c&3)*8;
      *(half8*)(&Bs[row*32+off]) = *(const half8*)(&W1T[(size_t)row*256 + k0 + off]);
    }
    __syncthreads();
    half8 af[2], bf[4];
    #pragma unroll
    for (int nt=0;nt<4;nt++) bf[nt] = *(const half8*)(&Bs[(nt*16+lm)*32 + quad*8]);
    #pragma unroll
    for (int mt=0;mt<2;mt++) af[mt] = *(const half8*)(&As[(wm0+mt*16+lm)*32 + quad*8]);
    #pragma unroll
    for (int mt=0;mt<2;mt++)
      #pragma unroll
      for (int nt=0;nt<4;nt++)
        acc[mt][nt] = __builtin_amdgcn_mfma_f32_16x16x32_f16(af[mt], bf[nt], acc[mt][nt], 0,0,0);
    __syncthreads();
  }
  float b1v[4], w20[4], w21[4];
  #pragma unroll
  for (int nt=0;nt<4;nt++){
    int n = nt*16+lm;
    b1v[nt]=b1[n]; w20[nt]=W2[n*2]; w21[nt]=W2[n*2+1];
  }
  float b20=b2[0], b21=b2[1];
  #pragma unroll
  for (int mt=0;mt<2;mt++)
   #pragma unroll
   for (int r=0;r<4;r++){
    int m = m0+wm0+mt*16+quad*4+r;
    float p0=0.f, p1=0.f;
    #pragma unroll
    for (int nt=0;nt<4;nt++){
      float v = acc[mt][nt][r] + b1v[nt];
      v = v>0.f? v : 0.f;
      p0 += v*w20[nt]; p1 += v*w21[nt];
    }
    p0 += __shfl_xor(p0,1); p0 += __shfl_xor(p0,2); p0 += __shfl_xor(p0,4); p0 += __shfl_xor(p0,8);
    p1 += __shfl_xor(p1,1); p1 += __shfl_xor(p1,2); p1 += __shfl_xor(p1,4); p1 += __shfl_xor(p1,8);
    if (lm==0){
      out[(size_t)m*2]   = p0 + b20;
      out[(size_t)m*2+1] = p1 + b21;
    }
  }
}

// ---------------- fused GRU recurrence + next-chunk gx GEMM ----------------
__global__ __launch_bounds__(512,1) void gru_fused(
    const half_t* __restrict__ whh16, const float* __restrict__ bhh_f, const float* __restrict__ bhh_b,
    const half_t* __restrict__ gxf, const half_t* __restrict__ gxb,
    float* __restrict__ hstate, half_t* __restrict__ y, int c, int gruBlocks,
    const half_t* __restrict__ hjk, const half_t* __restrict__ BcombT, const float* __restrict__ biasc,
    half_t* __restrict__ gxf_n, half_t* __restrict__ gxb_n, int s0f, int s0b){
  __shared__ half_t h16[2][16][132];
  __shared__ half_t As[128*32];
  __shared__ half_t Bs[128*32];
  const int bid = blockIdx.x;
  const int tid = threadIdx.x;
  if (bid < gruBlocks){
    // ---------------- GRU path ----------------
    const int d = bid >> 4, gblk = bid & 15;
    const half_t* __restrict__ gx = d ? gxb : gxf;
    const float* bhh = d ? bhh_b : bhh_f;
    const int w = tid >> 6, lane = tid & 63;
    const int l15 = lane & 15, quad = lane >> 4;
    const int unit = w*16 + l15;

    half8 bf[3][4];
    float bhn = bhh[256 + unit];
    {
      const half_t* wbase = whh16 + (size_t)d*49152;
      #pragma unroll
      for (int g=0; g<3; g++){
        const half_t* wp = wbase + (size_t)(g*128 + unit)*128;
        #pragma unroll
        for (int kk=0; kk<4; kk++)
          bf[g][kk] = *(const half8*)(wp + kk*32 + quad*8);
      }
    }

    float hreg[4];
    #pragma unroll
    for (int r=0;r<4;r++)
      hreg[r] = hstate[((size_t)d*256 + gblk*16 + quad*4 + r)*128 + unit];
    #pragma unroll
    for (int r=0;r<4;r++)
      h16[0][quad*4+r][unit] = (half_t)hreg[r];

    const int jstep = d ? -384 : 384;
    const int ystep = d ? -256 : 256;
    const int j0 = d ? 127 : 0;
    const int pos0 = d ? (511 - c*128) : (c*128);
    const int gr = gblk*16 + quad*4;
    int gvo[4], yvo[4];
    #pragma unroll
    for (int r=0;r<4;r++){
      gvo[r] = ((gr+r)*128 + j0)*384 + unit;
      yvo[r] = ((gr+r)*512 + pos0)*256 + d*128 + unit;
    }

    half_t gva[12], gvb[12];
    #pragma unroll
    for (int g=0;g<3;g++)
      #pragma unroll
      for (int r=0;r<4;r++) gva[g*4+r] = gx[gvo[r] + g*128];
    #pragma unroll
    for (int r=0;r<4;r++) gvo[r] += jstep;
    LDS_BARRIER();

    auto step = [&](int rd, int wr, half_t* gc, half_t* gn, bool pf){
      if (pf){
        #pragma unroll
        for (int g=0;g<3;g++)
          #pragma unroll
          for (int r=0;r<4;r++) gn[g*4+r] = gx[gvo[r] + g*128];
        #pragma unroll
        for (int r=0;r<4;r++) gvo[r] += jstep;
      }
      half8 af[4];
      #pragma unroll
      for (int kk=0;kk<4;kk++)
        af[kk] = *(const half8*)(&h16[rd][l15][kk*32 + quad*8]);
      f32x4 P[3] = {};
      #pragma unroll
      for (int kk=0;kk<4;kk++)
        #pragma unroll
        for (int g=0;g<3;g++)
          P[g] = __builtin_amdgcn_mfma_f32_16x16x32_f16(af[kk], bf[g][kk], P[g], 0,0,0);
      #pragma unroll
      for (int r=0;r<4;r++){
        float rr = sigm_((float)gc[0*4+r] + P[0][r]);
        float zz = sigm_((float)gc[1*4+r] + P[1][r]);
        float nn = tanh_((float)gc[2*4+r] + rr*(P[2][r] + bhn));
        float hn = nn + zz*(hreg[r]-nn);
        hreg[r] = hn;
        h16[wr][quad*4+r][unit] = (half_t)hn;
        y[yvo[r]] = (half_t)hn;
        yvo[r] += ystep;
      }
      LDS_BARRIER();
    };
    for (int it=0; it<63; it++){
      step(0,1,gva,gvb,true);
      step(1,0,gvb,gva,true);
    }
    step(0,1,gva,gvb,true);
    step(1,0,gvb,gva,false);
    #pragma unroll
    for (int r=0;r<4;r++)
      hstate[((size_t)d*256 + gblk*16 + quad*4 + r)*128 + unit] = hreg[r];
  } else {
    // ---------------- gemm path (512 threads, 8 waves) ----------------
    const int gb = bid - gruBlocks;
    const int bx = gb & 255, by = gb >> 8;       // 256 x 6
    const int m0 = bx*128;
    const bool back = by >= 3;
    const int n0 = (back ? by-3 : by)*128;
    const int step0 = back ? s0b : s0f;
    half_t* C = back ? gxb_n : gxf_n;
    const half_t* BTh = BcombT + (back ? (size_t)384*192 : 0);
    const float* bh = biasc + (back ? 384 : 0);
    const int w = tid>>6, lane = tid&63;
    const int lm = lane&15, quad = lane>>4;
    const int wm0 = (w>>2)*64, wn0 = (w&3)*32;
    f32x4 acc[4][2] = {};
    for (int k0=0; k0<192; k0+=32){
      {
        int cidx = tid; int row = cidx>>2; int off = (cidx&3)*8;
        int m = m0+row;
        size_t arow = (size_t)(m>>7)*512 + step0 + (m&127);
        *(half8*)(&As[row*32+off]) = *(const half8*)(&hjk[arow*192 + k0 + off]);
        *(half8*)(&Bs[row*32+off]) = *(const half8*)(&BTh[(size_t)(n0+row)*192 + k0 + off]);
      }
      __syncthreads();
      half8 af[4], bfr[2];
      #pragma unroll
      for (int nt=0;nt<2;nt++) bfr[nt] = *(const half8*)(&Bs[(wn0+nt*16+lm)*32 + quad*8]);
      #pragma unroll
      for (int mt=0;mt<4;mt++) af[mt] = *(const half8*)(&As[(wm0+mt*16+lm)*32 + quad*8]);
      #pragma unroll
      for (int mt=0;mt<4;mt++)
        #pragma unroll
        for (int nt=0;nt<2;nt++)
          acc[mt][nt] = __builtin_amdgcn_mfma_f32_16x16x32_f16(af[mt], bfr[nt], acc[mt][nt], 0,0,0);
      __syncthreads();
    }
    #pragma unroll
    for (int mt=0;mt<4;mt++)
     #pragma unroll
     for (int nt=0;nt<2;nt++)
      #pragma unroll
      for (int r=0;r<4;r++){
        int m = m0+wm0+mt*16+quad*4+r;
        int n = n0+wn0+nt*16+lm;
        float v = acc[mt][nt][r] + bh[n];
        C[(size_t)m*384 + n] = (half_t)v;
      }
  }
}

// ---------------- launch ----------------
extern "C" void kernel_launch(void* const* d_in, const int* in_sizes, int n_in,
                              void* d_out, int out_size, void* d_ws, size_t ws_size,
                              hipStream_t stream) {
  const float* x       = (const float*)d_in[0];
  const float* ea      = (const float*)d_in[1];
  const float* node_W  = (const float*)d_in[2];
  const float* node_b  = (const float*)d_in[3];
  const float* eW      = (const float*)d_in[4];
  const float* eb      = (const float*)d_in[5];
  const float* gat_W   = (const float*)d_in[6];
  const float* gat_We  = (const float*)d_in[7];
  const float* attS    = (const float*)d_in[8];
  const float* attD    = (const float*)d_in[9];
  const float* attE    = (const float*)d_in[10];
  const float* gat_b   = (const float*)d_in[11];
  const float* wih_f   = (const float*)d_in[12];
  const float* whh_f   = (const float*)d_in[13];
  const float* bih_f   = (const float*)d_in[14];
  const float* bhh_f   = (const float*)d_in[15];
  const float* wih_b   = (const float*)d_in[16];
  const float* whh_b   = (const float*)d_in[17];
  const float* bih_b   = (const float*)d_in[18];
  const float* bhh_b   = (const float*)d_in[19];
  const float* head_W1 = (const float*)d_in[20];
  const float* head_b1 = (const float*)d_in[21];
  const float* head_W2 = (const float*)d_in[22];
  const float* head_b2 = (const float*)d_in[23];
  const int*   ei      = (const int*)d_in[24];
  float* out = (float*)d_out;
  char* ws = (char*)d_ws;
  (void)in_sizes; (void)n_in; (void)out_size; (void)ws_size;

  size_t o = 0;
  auto alloc = [&](size_t bytes)->size_t{ size_t r=o; o += (bytes+255)&~(size_t)255; return r; };
  // persistent region
  size_t o_cc     = alloc(16*4);
  size_t o_biasc  = alloc(768*4);
  size_t o_BcombT = alloc((size_t)768*192*2);
  size_t o_BTgat  = alloc((size_t)3*4096*2);
  size_t o_W1T    = alloc((size_t)64*256*2);
  size_t o_whh16  = alloc((size_t)2*49152*2);
  size_t o_hstate = alloc((size_t)2*256*128*4);
  size_t shared_base = o;

  // GAT scratch inside shared region (dead before GRU phase)
  size_t o_deg    = alloc((size_t)NN*4);      // zeroed
  size_t zero_end = o;
  size_t o_tmp    = alloc((size_t)NE*4);
  size_t o_rows   = alloc((size_t)NN*4);
  size_t o_bsum   = alloc(512*4);
  size_t o_rec    = alloc((size_t)NE*16);
  size_t o_sw     = alloc((size_t)NE*8);
  size_t o_m01    = alloc((size_t)NN*8);
  size_t o_as     = alloc((size_t)NN*4);
  size_t o_ad     = alloc((size_t)NN*4);
  size_t o_h      = alloc((size_t)NN*64*2);
  size_t o_xp     = alloc((size_t)NN*64*2);
  size_t gat_end  = o;
  size_t gat_size = gat_end - shared_base;

  const size_t GXC    = (size_t)256*128*384*2;   // 25.17 MB per direction chunk
  const size_t HJK_SZ = (size_t)NN*192*2;        // 48 MB
  size_t shared_sz = gat_size > 4*GXC ? gat_size : 4*GXC;
  size_t o_gx0f = shared_base;               // aliases GAT scratch (dead by GRU phase)
  size_t o_gx0b = shared_base + GXC;
  size_t o_gx1f = shared_base + 2*GXC;
  size_t o_gx1b = shared_base + 3*GXC;
  size_t o_hjk = shared_base + shared_sz;
  size_t o_y   = o_hjk + HJK_SZ;

  int*    deg    = (int*)(ws+o_deg);
  int*    tmp    = (int*)(ws+o_tmp);
  int*    rows   = (int*)(ws+o_rows);
  int*    bsum   = (int*)(ws+o_bsum);
  int4*   rec    = (int4*)(ws+o_rec);
  int2*   sw     = (int2*)(ws+o_sw);
  float2* m01    = (float2*)(ws+o_m01);
  float*  a_s    = (float*)(ws+o_as);
  float*  a_d    = (float*)(ws+o_ad);
  float*  cc     = (float*)(ws+o_cc);
  float*  biasc  = (float*)(ws+o_biasc);
  half_t* h      = (half_t*)(ws+o_h);
  half_t* xp     = (half_t*)(ws+o_xp);
  half_t* hjk    = (half_t*)(ws+o_hjk);
  half_t* BcombT = (half_t*)(ws+o_BcombT);
  half_t* BTgat  = (half_t*)(ws+o_BTgat);
  half_t* W1T    = (half_t*)(ws+o_W1T);
  half_t* whh16  = (half_t*)(ws+o_whh16);
  float*  hstate = (float*)(ws+o_hstate);
  half_t* gxbuf[2][2] = {{(half_t*)(ws+o_gx0f), (half_t*)(ws+o_gx0b)},
                         {(half_t*)(ws+o_gx1f), (half_t*)(ws+o_gx1b)}};
  half_t* y      = (half_t*)(ws+o_y);

  hipMemsetAsync(ws+shared_base, 0, zero_end-shared_base, stream);   // deg
  hipMemsetAsync(ws+o_hstate, 0, (size_t)2*256*128*4, stream);       // GRU h init

  const_kernel<<<3,64,0,stream>>>(gat_We, attE, eW, eb, cc);
  prep_pack<<<1075,256,0,stream>>>(wih_f, wih_b, head_W1, gat_W, bih_f, bih_b, whh_f, whh_b,
                                   BcombT, W1T, BTgat, biasc, whh16);
  bias_fold<<<2,256,0,stream>>>(bhh_f, bhh_b, biasc);
  embed_kernel<<<32768,256,0,stream>>>(x, node_W, node_b, h);
  deg_count<<<4096,256,0,stream>>>(ei, deg, tmp);
  scan1<<<512,256,0,stream>>>(deg, rows, bsum);
  scan2<<<1,512,0,stream>>>(bsum);
  scan3<<<512,256,0,stream>>>(rows, bsum);
  fill2<<<4096,256,0,stream>>>(ei, ea, rows, tmp, rec);
  means_kernel<<<512,256,0,stream>>>(deg, rows, rec, m01);

  for (int l=0;l<3;l++){
    const half_t* in = (l==0)? h : (hjk + (size_t)(l-1)*64);
    int lda = (l==0)? 64 : 192;
    gemm_xp<<<1024,256,0,stream>>>(in, lda, BTgat + (size_t)l*4096, attS + l*64, attD + l*64, xp, a_s, a_d);
    edge_w<<<4096,256,0,stream>>>(rec, a_s, a_d, cc, l, sw);
    agg_lds<<<1024,512,0,stream>>>(rows, deg, sw, a_s, a_d, m01, cc, l, xp, gat_b + l*64, hjk);
  }

  // GRU: chunked, with next-chunk gemm fused as extra blocks
  gru_fused<<<1536,512,0,stream>>>(whh16, bhh_f, bhh_b, gxbuf[0][0], gxbuf[0][1], hstate, y, 0, 0,
                                   hjk, BcombT, biasc, gxbuf[0][0], gxbuf[0][1], 0, 384);
  for (int c=0;c<4;c++){
    int buf = c&1, nbuf = (c+1)&1;
    int grid = 32 + (c<3 ? 1536 : 0);
    gru_fused<<<grid,512,0,stream>>>(whh16, bhh_f, bhh_b, gxbuf[buf][0], gxbuf[buf][1], hstate, y, c, 32,
                                     hjk, BcombT, biasc, gxbuf[nbuf][0], gxbuf[nbuf][1],
                                     (c+1)*128, (2-c)*128);
  }

  gemm_head<<<1024,256,0,stream>>>(y, W1T, head_b1, head_W2, head_b2, out);
}

// Round 14
// 966.783 us; speedup vs baseline: 1.1270x; 1.0082x over previous
//
#include <hip/hip_runtime.h>
#include <cstdint>
#include <cstddef>

typedef _Float16 half_t;
typedef _Float16 half8 __attribute__((ext_vector_type(8)));
typedef float f32x4 __attribute__((ext_vector_type(4)));

constexpr int NN = 131072;    // nodes
constexpr int NE = 1048576;   // edges
constexpr int NPER = 512;

#define DEVINL __device__ __forceinline__

DEVINL float sigm_(float x){ float e = __expf(-x); return __builtin_amdgcn_rcpf(1.f+e); }
DEVINL float tanh_(float x){
  x = fminf(15.f, fmaxf(-15.f, x));
  float e = __expf(-2.f*x);
  return (1.f-e)*__builtin_amdgcn_rcpf(1.f+e);
}

// LDS-only barrier: no vmcnt drain (keeps global loads/stores in flight)
#define LDS_BARRIER() asm volatile("s_waitcnt lgkmcnt(0)\ns_barrier" ::: "memory")

// ---------------- tiny precompute kernels ----------------

__global__ void const_kernel(const float* __restrict__ gatWe,
                             const float* __restrict__ attE, const float* __restrict__ eW,
                             const float* __restrict__ eb, float* __restrict__ cc){
  int l = blockIdx.x, k = threadIdx.x;   // 3 blocks x 64 threads
  const float* Wel = gatWe + l*4096;
  float s3=0.f;
  for (int j=0;j<64;j++) s3 += Wel[k*64+j]*attE[l*64+j];
  float c0 = eW[k]*s3, c1 = eW[64+k]*s3, cb = eb[k]*s3;
  for (int off=1; off<64; off<<=1){
    c0 += __shfl_xor(c0,off); c1 += __shfl_xor(c1,off); cb += __shfl_xor(cb,off);
  }
  if (k==0){ cc[l]=c0; cc[3+l]=c1; cc[6+l]=cb; }
}

// pack/transpose weights to f16
__global__ void prep_pack(const float* __restrict__ wih_f, const float* __restrict__ wih_b,
                          const float* __restrict__ head_W1, const float* __restrict__ gat_W,
                          const float* __restrict__ bih_f, const float* __restrict__ bih_b,
                          const float* __restrict__ whh_f, const float* __restrict__ whh_b,
                          half_t* __restrict__ BcombT, half_t* __restrict__ W1T,
                          half_t* __restrict__ BTgat, float* __restrict__ bias_comb,
                          half_t* __restrict__ whh16){
  int gid = blockIdx.x*256 + threadIdx.x;
  if (gid < 147456){                       // BcombT: j<384 from wih_f else wih_b, k-contig
    int j = gid/192, k = gid%192;
    float v = (j<384)? wih_f[j*192+k] : wih_b[(j-384)*192+k];
    BcombT[gid] = (half_t)v;
  } else if (gid < 163840){                // W1T[n][k] = head_W1[k][n]
    int i = gid - 147456;
    int n = i>>8, k = i&255;
    W1T[i] = (half_t)head_W1[k*64+n];
  } else if (gid < 176128){                // BTgat[l][n][k] = gat_W[l][k][n]
    int i = gid - 163840;
    int l = i>>12, r = i&4095;
    int n = r>>6, k = r&63;
    BTgat[i] = (half_t)gat_W[l*4096 + k*64 + n];
  } else if (gid < 176896){
    int i = gid - 176128;                  // 0..767 (bih; bhh r,z folded by bias_fold)
    int j = (i<384)? i : i-384;
    bias_comb[i] = (i<384)? bih_f[j] : bih_b[j];
  } else if (gid < 275200){                // whh16: flat copy f then b (49152 each)
    int i = gid - 176896;
    float v = (i<49152)? whh_f[i] : whh_b[i-49152];
    whh16[i] = (half_t)v;
  }
}

__global__ void bias_fold(const float* __restrict__ bhh_f, const float* __restrict__ bhh_b,
                          float* __restrict__ bias_comb){
  int i = threadIdx.x + blockIdx.x*256;    // 0..511
  if (i < 256)      bias_comb[i]       += bhh_f[i];
  else if (i < 512) bias_comb[i+128]   += bhh_b[i-256];  // 384..639
}

// ---------------- node embedding ----------------
__global__ __launch_bounds__(256) void embed_kernel(const float* __restrict__ x,
                            const float* __restrict__ nW, const float* __restrict__ nb,
                            half_t* __restrict__ h){
  int gid = blockIdx.x*256 + threadIdx.x;
  int n = gid>>6, j = gid&63;
  float v = x[2*n]*nW[j] + x[2*n+1]*nW[64+j] + nb[j];
  h[(size_t)n*64+j] = (half_t)v;
}

// ---------------- edge preprocessing ----------------
__global__ __launch_bounds__(256) void deg_count(const int* __restrict__ ei,
                          int* __restrict__ deg, int* __restrict__ tmp){
  int e = blockIdx.x*256 + threadIdx.x;
  int dt = ei[NE+e];
  tmp[e] = atomicAdd(&deg[dt],1);
}

__global__ __launch_bounds__(256) void scan1(const int* __restrict__ deg, int* __restrict__ rowstart,
                      int* __restrict__ bsum){
  __shared__ int sc[256];
  int b=blockIdx.x, t=threadIdx.x, i=b*256+t;
  int v=deg[i]; sc[t]=v; __syncthreads();
  for (int off=1; off<256; off<<=1){
    int tv = (t>=off)? sc[t-off] : 0;
    __syncthreads(); sc[t]+=tv; __syncthreads();
  }
  rowstart[i]=sc[t]-v;
  if (t==255) bsum[b]=sc[255];
}
__global__ void scan2(int* __restrict__ bsum){   // 1 block x 512
  __shared__ int sc[512];
  int t=threadIdx.x; int v=bsum[t]; sc[t]=v; __syncthreads();
  for (int off=1; off<512; off<<=1){
    int tv = (t>=off)? sc[t-off] : 0;
    __syncthreads(); sc[t]+=tv; __syncthreads();
  }
  bsum[t]=sc[t]-v;
}
__global__ __launch_bounds__(256) void scan3(int* __restrict__ rowstart, const int* __restrict__ bsum){
  int b=blockIdx.x, t=threadIdx.x, i=b*256+t;
  rowstart[i]+=bsum[b];
}

// one 16B record per edge slot: {src, ea0, ea1, dst}
__global__ __launch_bounds__(256) void fill2(const int* __restrict__ ei, const float* __restrict__ ea,
                      const int* __restrict__ rowstart, const int* __restrict__ tmp,
                      int4* __restrict__ rec){
  int e = blockIdx.x*256 + threadIdx.x;
  int dt = ei[NE+e];
  int slot = rowstart[dt] + tmp[e];
  int4 r;
  r.x = ei[e];
  r.y = __float_as_int(ea[2*e]);
  r.z = __float_as_int(ea[2*e+1]);
  r.w = dt;
  rec[slot] = r;
}

__global__ __launch_bounds__(256) void means_kernel(const int* __restrict__ deg, const int* __restrict__ rowstart,
                         const int4* __restrict__ rec, float2* __restrict__ m01){
  int n = blockIdx.x*256 + threadIdx.x;
  int st = rowstart[n], cnt = deg[n];
  float s0=0.f, s1=0.f;
  for (int i=0;i<cnt;i++){
    int4 r = rec[st+i];
    s0 += __int_as_float(r.y);
    s1 += __int_as_float(r.z);
  }
  float inv = 1.f/(float)max(cnt,1);
  float2 m; m.x = s0*inv; m.y = s1*inv;
  m01[n] = m;
}

// ---------------- xp GEMM with fused attention-logit epilogue ----------------
__global__ __launch_bounds__(256) void gemm_xp(const half_t* __restrict__ A, int lda,
                        const half_t* __restrict__ BT,
                        const float* __restrict__ attS, const float* __restrict__ attD,
                        half_t* __restrict__ xp, float* __restrict__ a_s, float* __restrict__ a_d){
  __shared__ half_t As[128*32];
  __shared__ half_t Bs[64*32];
  const int tid = threadIdx.x, m0 = blockIdx.x*128;
  const int w = tid>>6, lane = tid&63;
  const int lm = lane&15, quad = lane>>4;
  const int wm0 = w*32;
  f32x4 acc[2][4] = {};
  for (int k0=0;k0<64;k0+=32){
    {
      const int c0 = tid*2;
      #pragma unroll
      for (int u=0;u<2;u++){
        int c=c0+u; int row=c>>2; int off=(c&3)*8;
        *(half8*)(&As[row*32+off]) = *(const half8*)(&A[(size_t)(m0+row)*lda + k0 + off]);
      }
      int c=tid; int row=c>>2; int off=(c&3)*8;
      *(half8*)(&Bs[row*32+off]) = *(const half8*)(&BT[(size_t)row*64 + k0 + off]);
    }
    __syncthreads();
    half8 af[2], bf[4];
    #pragma unroll
    for (int nt=0;nt<4;nt++) bf[nt] = *(const half8*)(&Bs[(nt*16+lm)*32 + quad*8]);
    #pragma unroll
    for (int mt=0;mt<2;mt++) af[mt] = *(const half8*)(&As[(wm0+mt*16+lm)*32 + quad*8]);
    #pragma unroll
    for (int mt=0;mt<2;mt++)
      #pragma unroll
      for (int nt=0;nt<4;nt++)
        acc[mt][nt] = __builtin_amdgcn_mfma_f32_16x16x32_f16(af[mt], bf[nt], acc[mt][nt], 0,0,0);
    __syncthreads();
  }
  float vsv[4], vdv[4];
  #pragma unroll
  for (int nt=0;nt<4;nt++){ vsv[nt]=attS[nt*16+lm]; vdv[nt]=attD[nt*16+lm]; }
  #pragma unroll
  for (int mt=0;mt<2;mt++)
   #pragma unroll
   for (int r=0;r<4;r++){
    int m = m0+wm0+mt*16+quad*4+r;
    float ps=0.f, pd=0.f;
    #pragma unroll
    for (int nt=0;nt<4;nt++){
      float v = acc[mt][nt][r];
      xp[(size_t)m*64 + nt*16+lm] = (half_t)v;
      ps += v*vsv[nt]; pd += v*vdv[nt];
    }
    ps += __shfl_xor(ps,1); ps += __shfl_xor(ps,2); ps += __shfl_xor(ps,4); ps += __shfl_xor(ps,8);
    pd += __shfl_xor(pd,1); pd += __shfl_xor(pd,2); pd += __shfl_xor(pd,4); pd += __shfl_xor(pd,8);
    if (lm==0){ a_s[m]=ps; a_d[m]=pd; }
  }
}

// ---------------- slot-parallel edge softmax weight ----------------
__global__ __launch_bounds__(256) void edge_w(const int4* __restrict__ rec,
                       const float* __restrict__ a_s, const float* __restrict__ a_d,
                       const float* __restrict__ cc, int l, int2* __restrict__ sw){
  int s = blockIdx.x*256 + threadIdx.x;
  int4 r = rec[s];
  float al = a_s[r.x] + a_d[r.w]
           + __int_as_float(r.y)*cc[l] + __int_as_float(r.z)*cc[3+l] + cc[6+l];
  al = al>0.f? al : 0.2f*al;
  int2 o; o.x = r.x; o.y = __float_as_int(__expf(al));
  sw[s] = o;
}

// ---------------- graph-local LDS aggregate: dual-chain walk ----------------
constexpr int SWCAP = 1536;
__global__ __launch_bounds__(512,4) void agg_lds(const int* __restrict__ rowstart, const int* __restrict__ deg,
                          const int2* __restrict__ sw,
                          const float* __restrict__ a_s, const float* __restrict__ a_d,
                          const float2* __restrict__ m01, const float* __restrict__ cc, int l,
                          const half_t* __restrict__ xp, const float* __restrict__ bias,
                          half_t* __restrict__ hjk){
  __shared__ half_t xs[512*64];   // 64 KB
  __shared__ int2  swl[SWCAP];    // 12 KB
  const int g = blockIdx.x >> 2;
  const int sub = blockIdx.x & 3;
  const int tid = threadIdx.x;
  const int nbase = g*512 + sub*128;
  const int segst = rowstart[nbase];
  const int segend = rowstart[nbase+127] + deg[nbase+127];
  const int segcnt = segend - segst;
  {
    const half8* srcp = (const half8*)(xp + (size_t)g*32768);
    half8* dstp = (half8*)xs;
    #pragma unroll
    for (int i=0;i<8;i++)
      dstp[tid + i*512] = srcp[tid + i*512];
    int scap = segcnt < SWCAP ? segcnt : SWCAP;
    for (int i=tid; i<scap; i+=512)
      swl[i] = sw[segst+i];
  }
  __syncthreads();
  const int w = tid>>6, lane = tid&63;
  const float bv = bias[lane];
  const float c0=cc[l], c1=cc[3+l], cb=cc[6+l];
  const int nb2 = nbase + w*16;
  for (int i=0;i<16;i++){
    int n = nb2 + i;
    int st = rowstart[n] - segst, cnt = deg[n];
    float acc=0.f, den=0.f;
    if (cnt>0){
      if (st + cnt <= SWCAP){
        // dual independent LDS chains (cnt is wave-uniform: no divergence)
        int cA = cnt>>1, cB = cnt-cA;            // cB >= cA
        int2 pB = swl[st+cA];
        float xvB = (float)xs[(pB.x&511)*64 + lane];
        int2 pA = pB; float xvA = 0.f;
        if (cA>0){ pA = swl[st]; xvA = (float)xs[(pA.x&511)*64 + lane]; }
        for (int k=0;k<cB;k++){
          int2 pBn = pB; float xvBn=0.f;
          if (k+1<cB){ pBn = swl[st+cA+k+1]; xvBn = (float)xs[(pBn.x&511)*64 + lane]; }
          int2 pAn = pA; float xvAn=0.f;
          if (k+1<cA){ pAn = swl[st+k+1]; xvAn = (float)xs[(pAn.x&511)*64 + lane]; }
          float wB = __int_as_float(pB.y); den += wB; acc += wB*xvB;
          pB = pBn; xvB = xvBn;
          if (k<cA){ float wA = __int_as_float(pA.y); den += wA; acc += wA*xvA; }
          pA = pAn; xvA = xvAn;
        }
      } else {
        // overflow path (essentially never taken)
        int2 p = sw[segst+st];
        float xv = (float)xs[(p.x&511)*64 + lane];
        for (int k=0;k<cnt;k++){
          int2 pn = p; float xvn=0.f;
          if (k+1<cnt){
            pn = sw[segst+st+k+1];
            xvn = (float)xs[(pn.x&511)*64 + lane];
          }
          float ww = __int_as_float(p.y);
          den += ww;
          acc += ww*xv;
          p = pn; xv = xvn;
        }
      }
    }
    float2 m = m01[n];
    float ael = cnt? (m.x*c0 + m.y*c1 + cb) : 0.f;
    float asl = a_s[n] + a_d[n] + ael;
    asl = asl>0.f? asl : 0.2f*asl;
    float wsf = __expf(asl);
    den += wsf;
    acc += wsf*(float)xs[(n&511)*64 + lane];
    float v = acc/den + bv;
    v = v>0.f? v : 0.01f*v;
    hjk[(size_t)n*192 + l*64 + lane] = (half_t)v;
  }
}

// ---------------- head GEMM with fused MLP-2 epilogue ----------------
__global__ __launch_bounds__(256) void gemm_head(const half_t* __restrict__ A,
                        const half_t* __restrict__ W1T, const float* __restrict__ b1,
                        const float* __restrict__ W2, const float* __restrict__ b2,
                        float* __restrict__ out){
  __shared__ half_t As[128*32];
  __shared__ half_t Bs[64*32];
  const int tid = threadIdx.x, m0 = blockIdx.x*128;
  const int w = tid>>6, lane = tid&63;
  const int lm = lane&15, quad = lane>>4;
  const int wm0 = w*32;
  f32x4 acc[2][4] = {};
  for (int k0=0;k0<256;k0+=32){
    {
      const int c0 = tid*2;
      #pragma unroll
      for (int u=0;u<2;u++){
        int c=c0+u; int row=c>>2; int off=(c&3)*8;
        *(half8*)(&As[row*32+off]) = *(const half8*)(&A[(size_t)(m0+row)*256 + k0 + off]);
      }
      int c=tid; int row=c>>2; int off=(c&3)*8;
      *(half8*)(&Bs[row*32+off]) = *(const half8*)(&W1T[(size_t)row*256 + k0 + off]);
    }
    __syncthreads();
    half8 af[2], bf[4];
    #pragma unroll
    for (int nt=0;nt<4;nt++) bf[nt] = *(const half8*)(&Bs[(nt*16+lm)*32 + quad*8]);
    #pragma unroll
    for (int mt=0;mt<2;mt++) af[mt] = *(const half8*)(&As[(wm0+mt*16+lm)*32 + quad*8]);
    #pragma unroll
    for (int mt=0;mt<2;mt++)
      #pragma unroll
      for (int nt=0;nt<4;nt++)
        acc[mt][nt] = __builtin_amdgcn_mfma_f32_16x16x32_f16(af[mt], bf[nt], acc[mt][nt], 0,0,0);
    __syncthreads();
  }
  float b1v[4], w20[4], w21[4];
  #pragma unroll
  for (int nt=0;nt<4;nt++){
    int n = nt*16+lm;
    b1v[nt]=b1[n]; w20[nt]=W2[n*2]; w21[nt]=W2[n*2+1];
  }
  float b20=b2[0], b21=b2[1];
  #pragma unroll
  for (int mt=0;mt<2;mt++)
   #pragma unroll
   for (int r=0;r<4;r++){
    int m = m0+wm0+mt*16+quad*4+r;
    float p0=0.f, p1=0.f;
    #pragma unroll
    for (int nt=0;nt<4;nt++){
      float v = acc[mt][nt][r] + b1v[nt];
      v = v>0.f? v : 0.f;
      p0 += v*w20[nt]; p1 += v*w21[nt];
    }
    p0 += __shfl_xor(p0,1); p0 += __shfl_xor(p0,2); p0 += __shfl_xor(p0,4); p0 += __shfl_xor(p0,8);
    p1 += __shfl_xor(p1,1); p1 += __shfl_xor(p1,2); p1 += __shfl_xor(p1,4); p1 += __shfl_xor(p1,8);
    if (lm==0){
      out[(size_t)m*2]   = p0 + b20;
      out[(size_t)m*2+1] = p1 + b21;
    }
  }
}

// ---------------- fused GRU recurrence + next-chunk gx GEMM ----------------
__global__ __launch_bounds__(512,1) void gru_fused(
    const half_t* __restrict__ whh16, const float* __restrict__ bhh_f, const float* __restrict__ bhh_b,
    const half_t* __restrict__ gxf, const half_t* __restrict__ gxb,
    float* __restrict__ hstate, half_t* __restrict__ y, int c, int gruBlocks,
    const half_t* __restrict__ hjk, const half_t* __restrict__ BcombT, const float* __restrict__ biasc,
    half_t* __restrict__ gxf_n, half_t* __restrict__ gxb_n, int s0f, int s0b){
  __shared__ half_t h16[2][16][132];
  __shared__ half_t As[128*32];
  __shared__ half_t Bs[128*32];
  const int bid = blockIdx.x;
  const int tid = threadIdx.x;
  if (bid < gruBlocks){
    // ---------------- GRU path ----------------
    const int d = bid >> 4, gblk = bid & 15;
    const half_t* __restrict__ gx = d ? gxb : gxf;
    const float* bhh = d ? bhh_b : bhh_f;
    const int w = tid >> 6, lane = tid & 63;
    const int l15 = lane & 15, quad = lane >> 4;
    const int unit = w*16 + l15;

    half8 bf[3][4];
    float bhn = bhh[256 + unit];
    {
      const half_t* wbase = whh16 + (size_t)d*49152;
      #pragma unroll
      for (int g=0; g<3; g++){
        const half_t* wp = wbase + (size_t)(g*128 + unit)*128;
        #pragma unroll
        for (int kk=0; kk<4; kk++)
          bf[g][kk] = *(const half8*)(wp + kk*32 + quad*8);
      }
    }

    float hreg[4];
    #pragma unroll
    for (int r=0;r<4;r++)
      hreg[r] = hstate[((size_t)d*256 + gblk*16 + quad*4 + r)*128 + unit];
    #pragma unroll
    for (int r=0;r<4;r++)
      h16[0][quad*4+r][unit] = (half_t)hreg[r];

    const int jstep = d ? -384 : 384;
    const int ystep = d ? -256 : 256;
    const int j0 = d ? 127 : 0;
    const int pos0 = d ? (511 - c*128) : (c*128);
    const int gr = gblk*16 + quad*4;
    int gvo[4];
    #pragma unroll
    for (int r=0;r<4;r++)
      gvo[r] = ((gr+r)*128 + j0)*384 + unit;

    // coalesced y-copy mapping: thread copies 4 halfs of one graph's h row
    const int cgg = tid>>5;            // graph-in-block 0..15
    const int cpart = (tid&31)*4;      // unit offset 0..124
    half_t* yptr = y + ((size_t)(gblk*16 + cgg)*512 + pos0)*256 + d*128 + cpart;

    half_t gva[12], gvb[12];
    #pragma unroll
    for (int g=0;g<3;g++)
      #pragma unroll
      for (int r=0;r<4;r++) gva[g*4+r] = gx[gvo[r] + g*128];
    #pragma unroll
    for (int r=0;r<4;r++) gvo[r] += jstep;
    LDS_BARRIER();

    auto step = [&](int rd, int wr, half_t* gc, half_t* gn, bool pf, bool cp){
      if (pf){
        #pragma unroll
        for (int g=0;g<3;g++)
          #pragma unroll
          for (int r=0;r<4;r++) gn[g*4+r] = gx[gvo[r] + g*128];
        #pragma unroll
        for (int r=0;r<4;r++) gvo[r] += jstep;
      }
      if (cp){
        // copy previous step's h (in h16[rd]) to y, coalesced 8B/thread
        uint2 hv = *(const uint2*)&h16[rd][cgg][cpart];
        *(uint2*)yptr = hv;
        yptr += ystep;
      }
      half8 af[4];
      #pragma unroll
      for (int kk=0;kk<4;kk++)
        af[kk] = *(const half8*)(&h16[rd][l15][kk*32 + quad*8]);
      f32x4 P[3] = {};
      #pragma unroll
      for (int kk=0;kk<4;kk++)
        #pragma unroll
        for (int g=0;g<3;g++)
          P[g] = __builtin_amdgcn_mfma_f32_16x16x32_f16(af[kk], bf[g][kk], P[g], 0,0,0);
      #pragma unroll
      for (int r=0;r<4;r++){
        float rr = sigm_((float)gc[0*4+r] + P[0][r]);
        float zz = sigm_((float)gc[1*4+r] + P[1][r]);
        float nn = tanh_((float)gc[2*4+r] + rr*(P[2][r] + bhn));
        float hn = nn + zz*(hreg[r]-nn);
        hreg[r] = hn;
        h16[wr][quad*4+r][unit] = (half_t)hn;
      }
      LDS_BARRIER();
    };
    step(0,1,gva,gvb,true,false);            // t=0
    step(1,0,gvb,gva,true,true);             // t=1 (copies h(0))
    for (int it=1; it<63; it++){
      step(0,1,gva,gvb,true,true);
      step(1,0,gvb,gva,true,true);
    }
    step(0,1,gva,gvb,true,true);             // t=126
    step(1,0,gvb,gva,false,true);            // t=127 (copies h(126))
    {
      // final copy: h(127) sits in h16[0]
      uint2 hv = *(const uint2*)&h16[0][cgg][cpart];
      *(uint2*)yptr = hv;
    }
    #pragma unroll
    for (int r=0;r<4;r++)
      hstate[((size_t)d*256 + gblk*16 + quad*4 + r)*128 + unit] = hreg[r];
  } else {
    // ---------------- gemm path (512 threads, 8 waves) ----------------
    const int gb = bid - gruBlocks;
    const int bx = gb & 255, by = gb >> 8;       // 256 x 6
    const int m0 = bx*128;
    const bool back = by >= 3;
    const int n0 = (back ? by-3 : by)*128;
    const int step0 = back ? s0b : s0f;
    half_t* C = back ? gxb_n : gxf_n;
    const half_t* BTh = BcombT + (back ? (size_t)384*192 : 0);
    const float* bh = biasc + (back ? 384 : 0);
    const int w = tid>>6, lane = tid&63;
    const int lm = lane&15, quad = lane>>4;
    const int wm0 = (w>>2)*64, wn0 = (w&3)*32;
    f32x4 acc[4][2] = {};
    for (int k0=0; k0<192; k0+=32){
      {
        int cidx = tid; int row = cidx>>2; int off = (cidx&3)*8;
        int m = m0+row;
        size_t arow = (size_t)(m>>7)*512 + step0 + (m&127);
        *(half8*)(&As[row*32+off]) = *(const half8*)(&hjk[arow*192 + k0 + off]);
        *(half8*)(&Bs[row*32+off]) = *(const half8*)(&BTh[(size_t)(n0+row)*192 + k0 + off]);
      }
      __syncthreads();
      half8 af[4], bfr[2];
      #pragma unroll
      for (int nt=0;nt<2;nt++) bfr[nt] = *(const half8*)(&Bs[(wn0+nt*16+lm)*32 + quad*8]);
      #pragma unroll
      for (int mt=0;mt<4;mt++) af[mt] = *(const half8*)(&As[(wm0+mt*16+lm)*32 + quad*8]);
      #pragma unroll
      for (int mt=0;mt<4;mt++)
        #pragma unroll
        for (int nt=0;nt<2;nt++)
          acc[mt][nt] = __builtin_amdgcn_mfma_f32_16x16x32_f16(af[mt], bfr[nt], acc[mt][nt], 0,0,0);
      __syncthreads();
    }
    #pragma unroll
    for (int mt=0;mt<4;mt++)
     #pragma unroll
     for (int nt=0;nt<2;nt++)
      #pragma unroll
      for (int r=0;r<4;r++){
        int m = m0+wm0+mt*16+quad*4+r;
        int n = n0+wn0+nt*16+lm;
        float v = acc[mt][nt][r] + bh[n];
        C[(size_t)m*384 + n] = (half_t)v;
      }
  }
}

// ---------------- launch ----------------
extern "C" void kernel_launch(void* const* d_in, const int* in_sizes, int n_in,
                              void* d_out, int out_size, void* d_ws, size_t ws_size,
                              hipStream_t stream) {
  const float* x       = (const float*)d_in[0];
  const float* ea      = (const float*)d_in[1];
  const float* node_W  = (const float*)d_in[2];
  const float* node_b  = (const float*)d_in[3];
  const float* eW      = (const float*)d_in[4];
  const float* eb      = (const float*)d_in[5];
  const float* gat_W   = (const float*)d_in[6];
  const float* gat_We  = (const float*)d_in[7];
  const float* attS    = (const float*)d_in[8];
  const float* attD    = (const float*)d_in[9];
  const float* attE    = (const float*)d_in[10];
  const float* gat_b   = (const float*)d_in[11];
  const float* wih_f   = (const float*)d_in[12];
  const float* whh_f   = (const float*)d_in[13];
  const float* bih_f   = (const float*)d_in[14];
  const float* bhh_f   = (const float*)d_in[15];
  const float* wih_b   = (const float*)d_in[16];
  const float* whh_b   = (const float*)d_in[17];
  const float* bih_b   = (const float*)d_in[18];
  const float* bhh_b   = (const float*)d_in[19];
  const float* head_W1 = (const float*)d_in[20];
  const float* head_b1 = (const float*)d_in[21];
  const float* head_W2 = (const float*)d_in[22];
  const float* head_b2 = (const float*)d_in[23];
  const int*   ei      = (const int*)d_in[24];
  float* out = (float*)d_out;
  char* ws = (char*)d_ws;
  (void)in_sizes; (void)n_in; (void)out_size; (void)ws_size;

  size_t o = 0;
  auto alloc = [&](size_t bytes)->size_t{ size_t r=o; o += (bytes+255)&~(size_t)255; return r; };
  // persistent region
  size_t o_cc     = alloc(16*4);
  size_t o_biasc  = alloc(768*4);
  size_t o_BcombT = alloc((size_t)768*192*2);
  size_t o_BTgat  = alloc((size_t)3*4096*2);
  size_t o_W1T    = alloc((size_t)64*256*2);
  size_t o_whh16  = alloc((size_t)2*49152*2);
  size_t o_hstate = alloc((size_t)2*256*128*4);
  size_t shared_base = o;

  // GAT scratch inside shared region (dead before GRU phase)
  size_t o_deg    = alloc((size_t)NN*4);      // zeroed
  size_t zero_end = o;
  size_t o_tmp    = alloc((size_t)NE*4);
  size_t o_rows   = alloc((size_t)NN*4);
  size_t o_bsum   = alloc(512*4);
  size_t o_rec    = alloc((size_t)NE*16);
  size_t o_sw     = alloc((size_t)NE*8);
  size_t o_m01    = alloc((size_t)NN*8);
  size_t o_as     = alloc((size_t)NN*4);
  size_t o_ad     = alloc((size_t)NN*4);
  size_t o_h      = alloc((size_t)NN*64*2);
  size_t o_xp     = alloc((size_t)NN*64*2);
  size_t gat_end  = o;
  size_t gat_size = gat_end - shared_base;

  const size_t GXC    = (size_t)256*128*384*2;   // 25.17 MB per direction chunk
  const size_t HJK_SZ = (size_t)NN*192*2;        // 48 MB
  size_t shared_sz = gat_size > 4*GXC ? gat_size : 4*GXC;
  size_t o_gx0f = shared_base;               // aliases GAT scratch (dead by GRU phase)
  size_t o_gx0b = shared_base + GXC;
  size_t o_gx1f = shared_base + 2*GXC;
  size_t o_gx1b = shared_base + 3*GXC;
  size_t o_hjk = shared_base + shared_sz;
  size_t o_y   = o_hjk + HJK_SZ;

  int*    deg    = (int*)(ws+o_deg);
  int*    tmp    = (int*)(ws+o_tmp);
  int*    rows   = (int*)(ws+o_rows);
  int*    bsum   = (int*)(ws+o_bsum);
  int4*   rec    = (int4*)(ws+o_rec);
  int2*   sw     = (int2*)(ws+o_sw);
  float2* m01    = (float2*)(ws+o_m01);
  float*  a_s    = (float*)(ws+o_as);
  float*  a_d    = (float*)(ws+o_ad);
  float*  cc     = (float*)(ws+o_cc);
  float*  biasc  = (float*)(ws+o_biasc);
  half_t* h      = (half_t*)(ws+o_h);
  half_t* xp     = (half_t*)(ws+o_xp);
  half_t* hjk    = (half_t*)(ws+o_hjk);
  half_t* BcombT = (half_t*)(ws+o_BcombT);
  half_t* BTgat  = (half_t*)(ws+o_BTgat);
  half_t* W1T    = (half_t*)(ws+o_W1T);
  half_t* whh16  = (half_t*)(ws+o_whh16);
  float*  hstate = (float*)(ws+o_hstate);
  half_t* gxbuf[2][2] = {{(half_t*)(ws+o_gx0f), (half_t*)(ws+o_gx0b)},
                         {(half_t*)(ws+o_gx1f), (half_t*)(ws+o_gx1b)}};
  half_t* y      = (half_t*)(ws+o_y);

  hipMemsetAsync(ws+shared_base, 0, zero_end-shared_base, stream);   // deg
  hipMemsetAsync(ws+o_hstate, 0, (size_t)2*256*128*4, stream);       // GRU h init

  const_kernel<<<3,64,0,stream>>>(gat_We, attE, eW, eb, cc);
  prep_pack<<<1075,256,0,stream>>>(wih_f, wih_b, head_W1, gat_W, bih_f, bih_b, whh_f, whh_b,
                                   BcombT, W1T, BTgat, biasc, whh16);
  bias_fold<<<2,256,0,stream>>>(bhh_f, bhh_b, biasc);
  embed_kernel<<<32768,256,0,stream>>>(x, node_W, node_b, h);
  deg_count<<<4096,256,0,stream>>>(ei, deg, tmp);
  scan1<<<512,256,0,stream>>>(deg, rows, bsum);
  scan2<<<1,512,0,stream>>>(bsum);
  scan3<<<512,256,0,stream>>>(rows, bsum);
  fill2<<<4096,256,0,stream>>>(ei, ea, rows, tmp, rec);
  means_kernel<<<512,256,0,stream>>>(deg, rows, rec, m01);

  for (int l=0;l<3;l++){
    const half_t* in = (l==0)? h : (hjk + (size_t)(l-1)*64);
    int lda = (l==0)? 64 : 192;
    gemm_xp<<<1024,256,0,stream>>>(in, lda, BTgat + (size_t)l*4096, attS + l*64, attD + l*64, xp, a_s, a_d);
    edge_w<<<4096,256,0,stream>>>(rec, a_s, a_d, cc, l, sw);
    agg_lds<<<1024,512,0,stream>>>(rows, deg, sw, a_s, a_d, m01, cc, l, xp, gat_b + l*64, hjk);
  }

  // GRU: chunked, with next-chunk gemm fused as extra blocks
  gru_fused<<<1536,512,0,stream>>>(whh16, bhh_f, bhh_b, gxbuf[0][0], gxbuf[0][1], hstate, y, 0, 0,
                                   hjk, BcombT, biasc, gxbuf[0][0], gxbuf[0][1], 0, 384);
  for (int c=0;c<4;c++){
    int buf = c&1, nbuf = (c+1)&1;
    int grid = 32 + (c<3 ? 1536 : 0);
    gru_fused<<<grid,512,0,stream>>>(whh16, bhh_f, bhh_b, gxbuf[buf][0], gxbuf[buf][1], hstate, y, c, 32,
                                     hjk, BcombT, biasc, gxbuf[nbuf][0], gxbuf[nbuf][1],
                                     (c+1)*128, (2-c)*128);
  }

  gemm_head<<<1024,256,0,stream>>>(y, W1T, head_b1, head_W2, head_b2, out);
}